// Round 13
// baseline (177.177 us; speedup 1.0000x reference)
//
#include <hip/hip_runtime.h>
#include <math.h>

#define DD 1024
#define HH 2048
#define NCB 256

typedef float f32x4 __attribute__((ext_vector_type(4)));
typedef short short8 __attribute__((ext_vector_type(8)));
typedef unsigned long long ull;

__device__ __forceinline__ float b2f(unsigned short u) {
    return __uint_as_float(((unsigned int)u) << 16);
}
__device__ __forceinline__ unsigned short f2b(float f) {
    unsigned int x = __float_as_uint(f);
    unsigned int r = (x + 0x7FFFu + ((x >> 16) & 1u)) >> 16;
    return (unsigned short)r;
}
__device__ __forceinline__ ull ald64(const ull* p) {
    return __hip_atomic_load(p, __ATOMIC_RELAXED, __HIP_MEMORY_SCOPE_AGENT);
}
__device__ __forceinline__ void ast64(ull* p, ull v) {
    __hip_atomic_store(p, v, __ATOMIC_RELAXED, __HIP_MEMORY_SCOPE_AGENT);
}
__device__ __forceinline__ ull pkh(float h, unsigned g) {
    return ((ull)g << 32) | (ull)(unsigned)__float_as_uint(h);
}
__device__ __forceinline__ float loh(ull v) {
    return __uint_as_float((unsigned)v);
}

// ---------------- merged precompute (single launch):
// [0,256) gemm M,P + c1,A1 (reads W1 fp32 directly, XCD-clustered) |
// [256,1280) W2T | [1280,1792) W3T ; blocks 256..259 also zero tag arrays/sync
__global__ __launch_bounds__(256) void k_gemmPT(const float* __restrict__ W1,
                                                const float* __restrict__ W2,
                                                const float* __restrict__ W3,
                                                const float* __restrict__ b3,
                                                const float* __restrict__ x0,
                                                unsigned short* __restrict__ Mb,
                                                unsigned short* __restrict__ Pb,
                                                unsigned short* __restrict__ W2T,
                                                unsigned short* __restrict__ W3T,
                                                float* __restrict__ c1,
                                                float* __restrict__ A1g,
                                                float* __restrict__ h1t,
                                                float* __restrict__ h2t,
                                                float* __restrict__ hacct,
                                                unsigned* __restrict__ sync) {
    const int b = blockIdx.x, t = threadIdx.x;
    if (b >= 256) {
        int bb = b - 256;
        // zero-duty: tag arrays (float2[2048] each) + sync
        if (bb == 0) { float4 z = make_float4(0, 0, 0, 0); for (int q = 0; q < 4; ++q) ((float4*)h1t)[t * 4 + q] = z; }
        else if (bb == 1) { float4 z = make_float4(0, 0, 0, 0); for (int q = 0; q < 4; ++q) ((float4*)h2t)[t * 4 + q] = z; }
        else if (bb == 2) { float4 z = make_float4(0, 0, 0, 0); for (int q = 0; q < 4; ++q) ((float4*)hacct)[t * 4 + q] = z; }
        else if (bb == 3) { if (t < 512) sync[t] = 0u; }
        __shared__ float tile[64][65];
        const float* in; unsigned short* out; int R, C, bx, by;
        if (bb < 1024) { in = W2; out = W2T; R = HH; C = HH; bx = bb & 31; by = bb >> 5; }
        else           { bb -= 1024; in = W3; out = W3T; R = HH; C = DD; bx = bb & 15; by = bb >> 4; }
        const int c0 = bx * 64, r0 = by * 64;
        const int cc = t & 63, rb = t >> 6;
        #pragma unroll
        for (int p = 0; p < 16; ++p) {
            int rr = p * 4 + rb;
            tile[rr][cc] = in[(size_t)(r0 + rr) * C + c0 + cc];
        }
        __syncthreads();
        #pragma unroll
        for (int p = 0; p < 16; ++p) {
            int rr = p * 4 + rb;
            out[(size_t)(c0 + rr) * R + r0 + cc] = f2b(tile[cc][rr]);
        }
        return;
    }
    // ---- gemm: M = W1^T W3^T, P = M .* W2; c1 = W1^T b3; A1 = W1^T x0 ----
    __shared__ unsigned short At[128][40];
    __shared__ unsigned short Bt[128][40];
    const int m0 = (b & 15) * 128;   // same-m0 blocks share an XCD -> W1 slice L2-resident
    const int k0 = (b >> 4) * 128;
    const int r = t & 127, half = t >> 7;
    const int wv = t >> 6, l = t & 63;
    const int wr = wv >> 1, wc = wv & 1;
    const int fr = l & 15, fg = l >> 4;
    const bool do_aux = ((b >> 4) == 0) && (t < 128);
    float c1acc = 0.f, a1acc = 0.f;

    f32x4 acc[4][4] = {};
    for (int i0 = 0; i0 < DD; i0 += 32) {
        // A: At[m][i] = bf16(W1[i0+i][m0+m]) — strided gather, coalesced over m
        {
            const float* wp = W1 + (size_t)(i0 + half * 16) * HH + m0 + r;
            float v[16];
            #pragma unroll
            for (int k2 = 0; k2 < 16; ++k2) v[k2] = wp[(size_t)k2 * HH];
            short8 o0, o1;
            #pragma unroll
            for (int e = 0; e < 8; ++e) { o0[e] = (short)f2b(v[e]); o1[e] = (short)f2b(v[8 + e]); }
            *(short8*)&At[r][half * 16] = o0;
            *(short8*)&At[r][half * 16 + 8] = o1;
        }
        // B: Bt[k][i] = bf16(W3[k0+k][i0+i]) — contiguous fp32, convert
        {
            const float4* sbf = (const float4*)(W3 + (size_t)(k0 + r) * DD + i0 + half * 16);
            float4 f0 = sbf[0], f1 = sbf[1], f2v = sbf[2], f3 = sbf[3];
            short8 o0, o1;
            o0[0] = (short)f2b(f0.x); o0[1] = (short)f2b(f0.y); o0[2] = (short)f2b(f0.z); o0[3] = (short)f2b(f0.w);
            o0[4] = (short)f2b(f1.x); o0[5] = (short)f2b(f1.y); o0[6] = (short)f2b(f1.z); o0[7] = (short)f2b(f1.w);
            o1[0] = (short)f2b(f2v.x); o1[1] = (short)f2b(f2v.y); o1[2] = (short)f2b(f2v.z); o1[3] = (short)f2b(f2v.w);
            o1[4] = (short)f2b(f3.x); o1[5] = (short)f2b(f3.y); o1[6] = (short)f2b(f3.z); o1[7] = (short)f2b(f3.w);
            *(short8*)&Bt[r][half * 16] = o0;
            *(short8*)&Bt[r][half * 16 + 8] = o1;
        }
        __syncthreads();
        if (do_aux) {
            #pragma unroll
            for (int i = 0; i < 32; ++i) {
                float w1v = b2f(At[t][i]);
                c1acc += w1v * b3[i0 + i];
                a1acc += w1v * x0[i0 + i];
            }
        }
        short8 af[4], bf[4];
        #pragma unroll
        for (int a = 0; a < 4; ++a)
            af[a] = *(const short8*)&At[wr * 64 + a * 16 + fr][fg * 8];
        #pragma unroll
        for (int bq = 0; bq < 4; ++bq)
            bf[bq] = *(const short8*)&Bt[wc * 64 + bq * 16 + fr][fg * 8];
        #pragma unroll
        for (int a = 0; a < 4; ++a)
            #pragma unroll
            for (int bq = 0; bq < 4; ++bq)
                acc[a][bq] = __builtin_amdgcn_mfma_f32_16x16x32_bf16(af[a], bf[bq], acc[a][bq], 0, 0, 0);
        __syncthreads();
    }
    if (do_aux) { c1[m0 + t] = c1acc; A1g[m0 + t] = a1acc; }
    #pragma unroll
    for (int a = 0; a < 4; ++a) {
        #pragma unroll
        for (int bq = 0; bq < 4; ++bq) {
            #pragma unroll
            for (int j = 0; j < 4; ++j) {
                int row = m0 + wr * 64 + a * 16 + fg * 4 + j;
                int col = k0 + wc * 64 + bq * 16 + fr;
                size_t idx = (size_t)row * HH + col;
                float m = acc[a][bq][j];
                Mb[idx] = f2b(m);
                Pb[idx] = f2b(m * W2[idx]);
            }
        }
    }
}

// ---------------- persistent RK4 chain: data-flow tags, zero barriers ----------------
__global__ __launch_bounds__(256, 1) void k_chain(
    const unsigned short* __restrict__ Mb,   // [2048][2048]
    const unsigned short* __restrict__ Pb,   // [2048][2048]
    const unsigned short* __restrict__ W2T,  // [2048][2048]
    const unsigned short* __restrict__ W3T,  // [1024][2048]
    const float* __restrict__ x0,
    const float* __restrict__ b1, const float* __restrict__ wt,
    const float* __restrict__ b2, const float* __restrict__ b3,
    const float* __restrict__ c1, const float* __restrict__ A1g,
    ull* __restrict__ h1t, ull* __restrict__ h2t, ull* __restrict__ hacct,
    float* __restrict__ out,
    unsigned* __restrict__ sync) {
    __shared__ unsigned short Ms[8][2048];   // 32 KB
    __shared__ unsigned short Ps[8][2048];   // 32 KB
    __shared__ unsigned short Qs[8][2048];   // 32 KB
    __shared__ float vecH[2048];             // 8 KB
    __shared__ float vecW[2048];             // 8 KB
    __shared__ float wred[4];
    const int t = threadIdx.x, b = blockIdx.x;
    const int wib = t >> 6, lane = t & 63;
    const int gw2 = (b << 3) + (wib << 1);    // 2 h-rows per wave
    const int jx = (b << 2) + wib;            // 1 x-row per wave

    // ---- preload weight rows into LDS (wave-private) ----
    {
        const unsigned short* mp = Mb + (size_t)gw2 * HH;
        const unsigned short* pp = Pb + (size_t)gw2 * HH;
        const unsigned short* qp = W2T + (size_t)gw2 * HH;
        #pragma unroll
        for (int rep = 0; rep < 4; ++rep) {
            const int idx = rep * 512 + lane * 8;
            *(short8*)&Ms[wib * 2][idx]     = *(const short8*)(mp + idx);
            *(short8*)&Ms[wib * 2 + 1][idx] = *(const short8*)(mp + HH + idx);
            *(short8*)&Ps[wib * 2][idx]     = *(const short8*)(pp + idx);
            *(short8*)&Ps[wib * 2 + 1][idx] = *(const short8*)(pp + HH + idx);
            *(short8*)&Qs[wib * 2][idx]     = *(const short8*)(qp + idx);
            *(short8*)&Qs[wib * 2 + 1][idx] = *(const short8*)(qp + HH + idx);
        }
    }

    const float bb1_0 = b1[gw2], bb1_1 = b1[gw2 + 1];
    const float wt_0 = wt[gw2], wt_1 = wt[gw2 + 1];
    const float bb2_0 = b2[gw2], bb2_1 = b2[gw2 + 1];
    const float c1_0 = c1[gw2], c1_1 = c1[gw2 + 1];

    float A1_0 = 0.f, A1_1 = 0.f;
    float u0 = 0.f, u1 = 0.f;
    float hc0 = 0.f, hc1 = 0.f;
    float wdiv = 0.f;

    float logq_r = 0.f;
    if (b == 0 && wib == 0) {
        float ssum = 0.f;
        #pragma unroll
        for (int q = 0; q < 16; ++q) { float xv = x0[lane + (q << 6)]; ssum += xv * xv; }
        #pragma unroll
        for (int o = 1; o < 64; o <<= 1) ssum += __shfl_xor(ssum, o, 64);
        logq_r = -0.5f * ssum - 0.5f * 1024.0f * 1.8378770664093453f;
    }

    for (int s = 0; s < 8; ++s) {
        const int ss = s & 3;
        const float tcur = (s >> 2) * 0.5f + ((ss == 0) ? 0.f : (ss == 3) ? 0.5f : 0.25f);
        const unsigned tagA = 2 * s + 1;      // h1 tag this stage
        const unsigned tagB = 2 * s + 2;      // h2/hacc tag this stage

        // ================= Phase A: h1 (+ div ride-along for stage s-1) =================
        if (s == 0) {
            A1_0 = A1g[gw2]; A1_1 = A1g[gw2 + 1];
            float h0 = tanhf(A1_0 + bb1_0 + tcur * wt_0);
            float h1v = tanhf(A1_1 + bb1_1 + tcur * wt_1);
            u0 = 1.f - h0 * h0; u1 = 1.f - h1v * h1v;
            if (lane == 0) { ast64(h1t + gw2, pkh(h0, tagA)); ast64(h1t + gw2 + 1, pkh(h1v, tagA)); }
        } else {
            const unsigned need = 2 * s;      // h2 (and hacc) tag from stage s-1
            ull va[8];
            #pragma unroll
            for (int q = 0; q < 8; ++q) va[q] = ald64(h2t + t + (q << 8));
            #pragma unroll
            for (int q = 0; q < 8; ++q)
                while ((unsigned)(va[q] >> 32) < need) { __builtin_amdgcn_s_sleep(1); va[q] = ald64(h2t + t + (q << 8)); }
            if (ss == 0) {
                ull vb[8];
                #pragma unroll
                for (int q = 0; q < 8; ++q) vb[q] = ald64(hacct + t + (q << 8));
                #pragma unroll
                for (int q = 0; q < 8; ++q)
                    while ((unsigned)(vb[q] >> 32) < need) { __builtin_amdgcn_s_sleep(1); vb[q] = ald64(hacct + t + (q << 8)); }
                #pragma unroll
                for (int q = 0; q < 8; ++q) {
                    int i = t + (q << 8);
                    float h2v = loh(va[q]);
                    vecW[i] = 1.f - h2v * h2v;
                    vecH[i] = loh(vb[q]);
                }
            } else {
                #pragma unroll
                for (int q = 0; q < 8; ++q) {
                    int i = t + (q << 8);
                    float h2v = loh(va[q]);
                    vecW[i] = 1.f - h2v * h2v;
                    vecH[i] = h2v;
                }
            }
            __syncthreads();
            float md0 = 0.f, md1 = 0.f, pd0 = 0.f, pd1 = 0.f;
            #pragma unroll
            for (int rep = 0; rep < 4; ++rep) {
                const int idx = rep * 512 + lane * 8;
                float4 hA = *(const float4*)(vecH + idx);
                float4 hB = *(const float4*)(vecH + idx + 4);
                float4 wA = *(const float4*)(vecW + idx);
                float4 wB = *(const float4*)(vecW + idx + 4);
                float hv[8] = {hA.x, hA.y, hA.z, hA.w, hB.x, hB.y, hB.z, hB.w};
                float wv[8] = {wA.x, wA.y, wA.z, wA.w, wB.x, wB.y, wB.z, wB.w};
                short8 m0v = *(const short8*)&Ms[wib * 2][idx];
                short8 m1v = *(const short8*)&Ms[wib * 2 + 1][idx];
                short8 p0v = *(const short8*)&Ps[wib * 2][idx];
                short8 p1v = *(const short8*)&Ps[wib * 2 + 1][idx];
                #pragma unroll
                for (int e = 0; e < 8; ++e) {
                    md0 += b2f((unsigned short)m0v[e]) * hv[e];
                    md1 += b2f((unsigned short)m1v[e]) * hv[e];
                    pd0 += b2f((unsigned short)p0v[e]) * wv[e];
                    pd1 += b2f((unsigned short)p1v[e]) * wv[e];
                }
            }
            #pragma unroll
            for (int o = 1; o < 64; o <<= 1) {
                md0 += __shfl_xor(md0, o, 64); md1 += __shfl_xor(md1, o, 64);
                pd0 += __shfl_xor(pd0, o, 64); pd1 += __shfl_xor(pd1, o, 64);
            }
            const int sp = (s - 1) & 3;
            const float cprev = (sp == 1 || sp == 2) ? (1.f / 6.f) : (1.f / 12.f);
            wdiv += cprev * (u0 * pd0 + u1 * pd1);
            float pre0, pre1;
            if (ss == 0) {                      // step boundary: A1 += M*hacc + dt*c1
                A1_0 += md0 + 0.5f * c1_0; A1_1 += md1 + 0.5f * c1_1;
                pre0 = A1_0 + bb1_0 + tcur * wt_0; pre1 = A1_1 + bb1_1 + tcur * wt_1;
            } else {
                const float a = (ss == 3) ? 0.5f : 0.25f;
                pre0 = A1_0 + a * (md0 + c1_0) + bb1_0 + tcur * wt_0;
                pre1 = A1_1 + a * (md1 + c1_1) + bb1_1 + tcur * wt_1;
            }
            float h0 = tanhf(pre0), h1v = tanhf(pre1);
            u0 = 1.f - h0 * h0; u1 = 1.f - h1v * h1v;
            if (lane == 0) { ast64(h1t + gw2, pkh(h0, tagA)); ast64(h1t + gw2 + 1, pkh(h1v, tagA)); }
        }

        // ================= Phase B: h2 = tanh(W2^T h1 + b2) =================
        {
            ull va[8];
            #pragma unroll
            for (int q = 0; q < 8; ++q) va[q] = ald64(h1t + t + (q << 8));
            #pragma unroll
            for (int q = 0; q < 8; ++q)
                while ((unsigned)(va[q] >> 32) < tagA) { __builtin_amdgcn_s_sleep(1); va[q] = ald64(h1t + t + (q << 8)); }
            #pragma unroll
            for (int q = 0; q < 8; ++q) vecH[t + (q << 8)] = loh(va[q]);
        }
        __syncthreads();
        {
            float a0 = 0.f, a1 = 0.f;
            #pragma unroll
            for (int rep = 0; rep < 4; ++rep) {
                const int idx = rep * 512 + lane * 8;
                float4 hA = *(const float4*)(vecH + idx);
                float4 hB = *(const float4*)(vecH + idx + 4);
                float hv[8] = {hA.x, hA.y, hA.z, hA.w, hB.x, hB.y, hB.z, hB.w};
                short8 r0 = *(const short8*)&Qs[wib * 2][idx];
                short8 r1 = *(const short8*)&Qs[wib * 2 + 1][idx];
                #pragma unroll
                for (int e = 0; e < 8; ++e) {
                    a0 += b2f((unsigned short)r0[e]) * hv[e];
                    a1 += b2f((unsigned short)r1[e]) * hv[e];
                }
            }
            #pragma unroll
            for (int o = 1; o < 64; o <<= 1) {
                a0 += __shfl_xor(a0, o, 64); a1 += __shfl_xor(a1, o, 64);
            }
            float q0 = tanhf(a0 + bb2_0), q1 = tanhf(a1 + bb2_1);
            const float cs = (ss == 1 || ss == 2) ? (1.f / 6.f) : (1.f / 12.f);
            hc0 += cs * q0; hc1 += cs * q1;
            if (lane == 0) {
                if (ss == 3) {
                    ast64(hacct + gw2, pkh(hc0, tagB));
                    ast64(hacct + gw2 + 1, pkh(hc1, tagB));
                }
                ast64(h2t + gw2, pkh(q0, tagB));
                ast64(h2t + gw2 + 1, pkh(q1, tagB));
            }
        }
        __syncthreads();   // vecH reuse safety for next phase
    }

    // ================= Epilogue: last div + x_out; logq via atomics =================
    {
        ull va[8], vb[8];
        #pragma unroll
        for (int q = 0; q < 8; ++q) { va[q] = ald64(h2t + t + (q << 8)); vb[q] = ald64(hacct + t + (q << 8)); }
        #pragma unroll
        for (int q = 0; q < 8; ++q) {
            while ((unsigned)(va[q] >> 32) < 16u) { __builtin_amdgcn_s_sleep(1); va[q] = ald64(h2t + t + (q << 8)); }
            while ((unsigned)(vb[q] >> 32) < 16u) { __builtin_amdgcn_s_sleep(1); vb[q] = ald64(hacct + t + (q << 8)); }
        }
        #pragma unroll
        for (int q = 0; q < 8; ++q) {
            int i = t + (q << 8);
            float h2v = loh(va[q]);
            vecW[i] = 1.f - h2v * h2v;
            vecH[i] = loh(vb[q]);
        }
        __syncthreads();
        float pd0 = 0.f, pd1 = 0.f, xo = 0.f;
        const unsigned short* Vr = W3T + (size_t)jx * HH;
        #pragma unroll
        for (int rep = 0; rep < 4; ++rep) {
            const int idx = rep * 512 + lane * 8;
            float4 cA = *(const float4*)(vecH + idx);
            float4 cB = *(const float4*)(vecH + idx + 4);
            float4 wA = *(const float4*)(vecW + idx);
            float4 wB = *(const float4*)(vecW + idx + 4);
            float cv[8] = {cA.x, cA.y, cA.z, cA.w, cB.x, cB.y, cB.z, cB.w};
            float wv[8] = {wA.x, wA.y, wA.z, wA.w, wB.x, wB.y, wB.z, wB.w};
            short8 p0v = *(const short8*)&Ps[wib * 2][idx];
            short8 p1v = *(const short8*)&Ps[wib * 2 + 1][idx];
            short8 vv = *(const short8*)(Vr + idx);
            #pragma unroll
            for (int e = 0; e < 8; ++e) {
                pd0 += b2f((unsigned short)p0v[e]) * wv[e];
                pd1 += b2f((unsigned short)p1v[e]) * wv[e];
                xo  += b2f((unsigned short)vv[e]) * cv[e];
            }
        }
        #pragma unroll
        for (int o = 1; o < 64; o <<= 1) {
            pd0 += __shfl_xor(pd0, o, 64); pd1 += __shfl_xor(pd1, o, 64);
            xo += __shfl_xor(xo, o, 64);
        }
        wdiv += (1.f / 12.f) * (u0 * pd0 + u1 * pd1);
        if (lane == 0) {
            out[jx] = x0[jx] + xo + b3[jx];
            wred[wib] = wdiv;
        }
    }
    __syncthreads();
    if (t == 0) {
        float dsum = wred[0] + wred[1] + wred[2] + wred[3];
        atomicAdd((float*)(sync + (b & 15) * 16), dsum);
        asm volatile("s_waitcnt vmcnt(0)" ::: "memory");
        atomicAdd(sync + 256, 1u);
    }
    if (b == 0 && wib == 0) {
        if (lane == 0) {
            while (__hip_atomic_load(sync + 256, __ATOMIC_RELAXED, __HIP_MEMORY_SCOPE_AGENT) < NCB)
                __builtin_amdgcn_s_sleep(2);
        }
        __syncthreads();   // no-op for other waves already past; safe ordering for wave 0
        float v = 0.f;
        if (lane < 16) {
            unsigned du = __hip_atomic_load(sync + lane * 16, __ATOMIC_RELAXED, __HIP_MEMORY_SCOPE_AGENT);
            v = __uint_as_float(du);
        }
        #pragma unroll
        for (int o = 1; o < 64; o <<= 1) v += __shfl_xor(v, o, 64);
        if (lane == 0) out[DD] = logq_r - v;
    }
}

extern "C" void kernel_launch(void* const* d_in, const int* in_sizes, int n_in,
                              void* d_out, int out_size, void* d_ws, size_t ws_size,
                              hipStream_t stream) {
    const float* x0 = (const float*)d_in[0];
    const float* W1 = (const float*)d_in[1];
    const float* b1 = (const float*)d_in[2];
    const float* wt = (const float*)d_in[3];
    const float* W2 = (const float*)d_in[4];
    const float* b2 = (const float*)d_in[5];
    const float* W3 = (const float*)d_in[6];
    const float* b3 = (const float*)d_in[7];
    float* out = (float*)d_out;

    char* ws = (char*)d_ws;
    const size_t MB = 1024 * 1024;
    unsigned short* Pb  = (unsigned short*)(ws);            // 8 MB
    unsigned short* W2T = (unsigned short*)(ws + 8 * MB);   // 8 MB
    unsigned short* W3T = (unsigned short*)(ws + 16 * MB);  // 4 MB
    unsigned short* Mb  = (unsigned short*)(ws + 20 * MB);  // 8 MB
    float* fb = (float*)(ws + 28 * MB);
    float* c1      = fb;                       // 2048
    float* A1g     = fb + 2048;                // 2048
    ull* h1t       = (ull*)(fb + 4096);        // 2048 x 8B
    ull* h2t       = (ull*)(fb + 8192);        // 2048 x 8B
    ull* hacct     = (ull*)(fb + 12288);       // 2048 x 8B
    unsigned* sync = (unsigned*)(fb + 16384);  // 512 uints

    k_gemmPT<<<1792, 256, 0, stream>>>(W1, W2, W3, b3, x0, Mb, Pb, W2T, W3T,
                                       c1, A1g, (float*)h1t, (float*)h2t, (float*)hacct, sync);
    k_chain<<<NCB, 256, 0, stream>>>(Mb, Pb, W2T, W3T, x0, b1, wt, b2, b3, c1, A1g,
                                     h1t, h2t, hacct, out, sync);
}

// Round 14
// 173.482 us; speedup vs baseline: 1.0213x; 1.0213x over previous
//
#include <hip/hip_runtime.h>
#include <math.h>

#define DD 1024
#define HH 2048
#define NCB 256

typedef float f32x4 __attribute__((ext_vector_type(4)));
typedef short short8 __attribute__((ext_vector_type(8)));

__device__ __forceinline__ float b2f(unsigned short u) {
    return __uint_as_float(((unsigned int)u) << 16);
}
__device__ __forceinline__ unsigned short f2b(float f) {
    unsigned int x = __float_as_uint(f);
    unsigned int r = (x + 0x7FFFu + ((x >> 16) & 1u)) >> 16;
    return (unsigned short)r;
}
__device__ __forceinline__ float ald(const float* p) {
    return __hip_atomic_load(p, __ATOMIC_RELAXED, __HIP_MEMORY_SCOPE_AGENT);
}
__device__ __forceinline__ void ast(float* p, float v) {
    __hip_atomic_store(p, v, __ATOMIC_RELAXED, __HIP_MEMORY_SCOPE_AGENT);
}

// ---------------- merged precompute (single launch):
// [0,256) gemm M,P + c1,A1 (W1 read directly, XCD-clustered m0) |
// [256,1280) W2T | [1280,1792) W3T ; block 256 zeroes sync
__global__ __launch_bounds__(256) void k_gemmPT(const float* __restrict__ W1,
                                                const float* __restrict__ W2,
                                                const float* __restrict__ W3,
                                                const float* __restrict__ b3,
                                                const float* __restrict__ x0,
                                                unsigned short* __restrict__ Mb,
                                                unsigned short* __restrict__ Pb,
                                                unsigned short* __restrict__ W2T,
                                                unsigned short* __restrict__ W3T,
                                                float* __restrict__ c1,
                                                float* __restrict__ A1g,
                                                unsigned* __restrict__ sync) {
    const int b = blockIdx.x, t = threadIdx.x;
    if (b >= 256) {
        int bb = b - 256;
        if (bb == 0) {
            #pragma unroll
            for (int q = 0; q < 18; ++q) {
                int i = t + q * 256;
                if (i < 4368) sync[i] = 0u;
            }
        }
        __shared__ float tile[64][65];
        const float* in; unsigned short* out; int R, C, bx, by;
        if (bb < 1024) { in = W2; out = W2T; R = HH; C = HH; bx = bb & 31; by = bb >> 5; }
        else           { bb -= 1024; in = W3; out = W3T; R = HH; C = DD; bx = bb & 15; by = bb >> 4; }
        const int c0 = bx * 64, r0 = by * 64;
        const int cc = t & 63, rb = t >> 6;
        #pragma unroll
        for (int p = 0; p < 16; ++p) {
            int rr = p * 4 + rb;
            tile[rr][cc] = in[(size_t)(r0 + rr) * C + c0 + cc];
        }
        __syncthreads();
        #pragma unroll
        for (int p = 0; p < 16; ++p) {
            int rr = p * 4 + rb;
            out[(size_t)(c0 + rr) * R + r0 + cc] = f2b(tile[cc][rr]);
        }
        return;
    }
    // ---- gemm: M = W1^T W3^T, P = M .* W2; c1 = W1^T b3; A1 = W1^T x0 ----
    __shared__ unsigned short At[128][40];
    __shared__ unsigned short Bt[128][40];
    const int m0 = (b & 15) * 128;   // same-m0 blocks share an XCD -> W1 slice L2-resident
    const int k0 = (b >> 4) * 128;
    const int r = t & 127, half = t >> 7;
    const int wv = t >> 6, l = t & 63;
    const int wr = wv >> 1, wc = wv & 1;
    const int fr = l & 15, fg = l >> 4;
    const bool do_aux = ((b >> 4) == 0) && (t < 128);
    float c1acc = 0.f, a1acc = 0.f;

    f32x4 acc[4][4] = {};
    for (int i0 = 0; i0 < DD; i0 += 32) {
        {
            const float* wp = W1 + (size_t)(i0 + half * 16) * HH + m0 + r;
            float v[16];
            #pragma unroll
            for (int k2 = 0; k2 < 16; ++k2) v[k2] = wp[(size_t)k2 * HH];
            short8 o0, o1;
            #pragma unroll
            for (int e = 0; e < 8; ++e) { o0[e] = (short)f2b(v[e]); o1[e] = (short)f2b(v[8 + e]); }
            *(short8*)&At[r][half * 16] = o0;
            *(short8*)&At[r][half * 16 + 8] = o1;
        }
        {
            const float4* sbf = (const float4*)(W3 + (size_t)(k0 + r) * DD + i0 + half * 16);
            float4 f0 = sbf[0], f1 = sbf[1], f2v = sbf[2], f3 = sbf[3];
            short8 o0, o1;
            o0[0] = (short)f2b(f0.x); o0[1] = (short)f2b(f0.y); o0[2] = (short)f2b(f0.z); o0[3] = (short)f2b(f0.w);
            o0[4] = (short)f2b(f1.x); o0[5] = (short)f2b(f1.y); o0[6] = (short)f2b(f1.z); o0[7] = (short)f2b(f1.w);
            o1[0] = (short)f2b(f2v.x); o1[1] = (short)f2b(f2v.y); o1[2] = (short)f2b(f2v.z); o1[3] = (short)f2b(f2v.w);
            o1[4] = (short)f2b(f3.x); o1[5] = (short)f2b(f3.y); o1[6] = (short)f2b(f3.z); o1[7] = (short)f2b(f3.w);
            *(short8*)&Bt[r][half * 16] = o0;
            *(short8*)&Bt[r][half * 16 + 8] = o1;
        }
        __syncthreads();
        if (do_aux) {
            #pragma unroll
            for (int i = 0; i < 32; ++i) {
                float w1v = b2f(At[t][i]);
                c1acc += w1v * b3[i0 + i];
                a1acc += w1v * x0[i0 + i];
            }
        }
        short8 af[4], bf[4];
        #pragma unroll
        for (int a = 0; a < 4; ++a)
            af[a] = *(const short8*)&At[wr * 64 + a * 16 + fr][fg * 8];
        #pragma unroll
        for (int bq = 0; bq < 4; ++bq)
            bf[bq] = *(const short8*)&Bt[wc * 64 + bq * 16 + fr][fg * 8];
        #pragma unroll
        for (int a = 0; a < 4; ++a)
            #pragma unroll
            for (int bq = 0; bq < 4; ++bq)
                acc[a][bq] = __builtin_amdgcn_mfma_f32_16x16x32_bf16(af[a], bf[bq], acc[a][bq], 0, 0, 0);
        __syncthreads();
    }
    if (do_aux) { c1[m0 + t] = c1acc; A1g[m0 + t] = a1acc; }
    #pragma unroll
    for (int a = 0; a < 4; ++a) {
        #pragma unroll
        for (int bq = 0; bq < 4; ++bq) {
            #pragma unroll
            for (int j = 0; j < 4; ++j) {
                int row = m0 + wr * 64 + a * 16 + fg * 4 + j;
                int col = k0 + wc * 64 + bq * 16 + fr;
                size_t idx = (size_t)row * HH + col;
                float m = acc[a][bq][j];
                Mb[idx] = f2b(m);
                Pb[idx] = f2b(m * W2[idx]);
            }
        }
    }
}

// ---------------- direct-scan grid barrier (agent scope, no checker) ----------------
// flags[b] = sync[b*16] (256 x 64B lines). Arrival: relaxed store (data already
// LLC-acked by __syncthreads' vmcnt drain). Wait: wave 0 scans all 256 flags,
// 4 per lane, pure atomic loads (no RMW serialization).
__device__ __forceinline__ void gbar(unsigned* sync, int b, unsigned g) {
    __syncthreads();
    if (threadIdx.x < 64) {
        if (threadIdx.x == 0) {
            asm volatile("s_waitcnt vmcnt(0)" ::: "memory");
            __hip_atomic_store(&sync[b << 4], g, __ATOMIC_RELAXED, __HIP_MEMORY_SCOPE_AGENT);
        }
        while (true) {
            bool ok = true;
            #pragma unroll
            for (int k = 0; k < 4; ++k) {
                unsigned f = __hip_atomic_load(&sync[(threadIdx.x + (k << 6)) << 4],
                                               __ATOMIC_RELAXED, __HIP_MEMORY_SCOPE_AGENT);
                ok &= (f >= g);
            }
            if (!__any((int)(!ok))) break;
            __builtin_amdgcn_s_sleep(1);
        }
    }
    __syncthreads();
}

// ---------------- persistent RK4 chain: weights in LDS, relaxed-atomic h exchange ----------------
__global__ __launch_bounds__(256, 1) void k_chain(
    const unsigned short* __restrict__ Mb,   // [2048][2048]
    const unsigned short* __restrict__ Pb,   // [2048][2048]
    const unsigned short* __restrict__ W2T,  // [2048][2048]
    const unsigned short* __restrict__ W3T,  // [1024][2048]
    const float* __restrict__ x0,
    const float* __restrict__ b1, const float* __restrict__ wt,
    const float* __restrict__ b2, const float* __restrict__ b3,
    const float* __restrict__ c1, const float* __restrict__ A1g,
    float* __restrict__ h1_g, float* __restrict__ h2_g, float* __restrict__ hacc_g,
    float* __restrict__ out,
    unsigned* __restrict__ sync) {
    __shared__ unsigned short Ms[8][2048];   // 32 KB
    __shared__ unsigned short Ps[8][2048];   // 32 KB
    __shared__ unsigned short Qs[8][2048];   // 32 KB
    __shared__ float vecH[2048];             // 8 KB
    __shared__ float vecW[2048];             // 8 KB
    __shared__ float wred[4];
    const int t = threadIdx.x, b = blockIdx.x;
    const int wib = t >> 6, lane = t & 63;
    const int gw2 = (b << 3) + (wib << 1);    // 2 h-rows per wave
    const int jx = (b << 2) + wib;            // 1 x-row per wave
    unsigned g = 0;

    {
        const unsigned short* mp = Mb + (size_t)gw2 * HH;
        const unsigned short* pp = Pb + (size_t)gw2 * HH;
        const unsigned short* qp = W2T + (size_t)gw2 * HH;
        #pragma unroll
        for (int rep = 0; rep < 4; ++rep) {
            const int idx = rep * 512 + lane * 8;
            *(short8*)&Ms[wib * 2][idx]     = *(const short8*)(mp + idx);
            *(short8*)&Ms[wib * 2 + 1][idx] = *(const short8*)(mp + HH + idx);
            *(short8*)&Ps[wib * 2][idx]     = *(const short8*)(pp + idx);
            *(short8*)&Ps[wib * 2 + 1][idx] = *(const short8*)(pp + HH + idx);
            *(short8*)&Qs[wib * 2][idx]     = *(const short8*)(qp + idx);
            *(short8*)&Qs[wib * 2 + 1][idx] = *(const short8*)(qp + HH + idx);
        }
    }

    const float bb1_0 = b1[gw2], bb1_1 = b1[gw2 + 1];
    const float wt_0 = wt[gw2], wt_1 = wt[gw2 + 1];
    const float bb2_0 = b2[gw2], bb2_1 = b2[gw2 + 1];
    const float c1_0 = c1[gw2], c1_1 = c1[gw2 + 1];

    float A1_0 = 0.f, A1_1 = 0.f;
    float u0 = 0.f, u1 = 0.f;
    float hc0 = 0.f, hc1 = 0.f;
    float wdiv = 0.f;

    float logq_r = 0.f;
    if (b == 0 && wib == 0) {
        float ssum = 0.f;
        #pragma unroll
        for (int q = 0; q < 16; ++q) { float xv = x0[lane + (q << 6)]; ssum += xv * xv; }
        #pragma unroll
        for (int o = 1; o < 64; o <<= 1) ssum += __shfl_xor(ssum, o, 64);
        logq_r = -0.5f * ssum - 0.5f * 1024.0f * 1.8378770664093453f;
    }

    for (int s = 0; s < 8; ++s) {
        const int ss = s & 3;
        const float tcur = (s >> 2) * 0.5f + ((ss == 0) ? 0.f : (ss == 3) ? 0.5f : 0.25f);

        // ================= Phase A: h1 (+ div ride-along for stage s-1) =================
        if (s == 0) {
            A1_0 = A1g[gw2]; A1_1 = A1g[gw2 + 1];
            float h0 = tanhf(A1_0 + bb1_0 + tcur * wt_0);
            float h1v = tanhf(A1_1 + bb1_1 + tcur * wt_1);
            u0 = 1.f - h0 * h0; u1 = 1.f - h1v * h1v;
            if (lane == 0) { ast(h1_g + gw2, h0); ast(h1_g + gw2 + 1, h1v); }
        } else {
            #pragma unroll
            for (int q = 0; q < 8; ++q) {
                int i = t + (q << 8);
                float h2v = ald(h2_g + i);
                float sv = (ss == 0) ? ald(hacc_g + i) : h2v;
                vecH[i] = sv;
                vecW[i] = 1.f - h2v * h2v;
            }
            __syncthreads();
            float md0 = 0.f, md1 = 0.f, pd0 = 0.f, pd1 = 0.f;
            #pragma unroll
            for (int rep = 0; rep < 4; ++rep) {
                const int idx = rep * 512 + lane * 8;
                float4 hA = *(const float4*)(vecH + idx);
                float4 hB = *(const float4*)(vecH + idx + 4);
                float4 wA = *(const float4*)(vecW + idx);
                float4 wB = *(const float4*)(vecW + idx + 4);
                float hv[8] = {hA.x, hA.y, hA.z, hA.w, hB.x, hB.y, hB.z, hB.w};
                float wv[8] = {wA.x, wA.y, wA.z, wA.w, wB.x, wB.y, wB.z, wB.w};
                short8 m0v = *(const short8*)&Ms[wib * 2][idx];
                short8 m1v = *(const short8*)&Ms[wib * 2 + 1][idx];
                short8 p0v = *(const short8*)&Ps[wib * 2][idx];
                short8 p1v = *(const short8*)&Ps[wib * 2 + 1][idx];
                #pragma unroll
                for (int e = 0; e < 8; ++e) {
                    md0 += b2f((unsigned short)m0v[e]) * hv[e];
                    md1 += b2f((unsigned short)m1v[e]) * hv[e];
                    pd0 += b2f((unsigned short)p0v[e]) * wv[e];
                    pd1 += b2f((unsigned short)p1v[e]) * wv[e];
                }
            }
            #pragma unroll
            for (int o = 1; o < 64; o <<= 1) {
                md0 += __shfl_xor(md0, o, 64); md1 += __shfl_xor(md1, o, 64);
                pd0 += __shfl_xor(pd0, o, 64); pd1 += __shfl_xor(pd1, o, 64);
            }
            const int sp = (s - 1) & 3;
            const float cprev = (sp == 1 || sp == 2) ? (1.f / 6.f) : (1.f / 12.f);
            wdiv += cprev * (u0 * pd0 + u1 * pd1);
            float pre0, pre1;
            if (ss == 0) {                      // step boundary: A1 += M*hacc + dt*c1
                A1_0 += md0 + 0.5f * c1_0; A1_1 += md1 + 0.5f * c1_1;
                pre0 = A1_0 + bb1_0 + tcur * wt_0; pre1 = A1_1 + bb1_1 + tcur * wt_1;
            } else {
                const float a = (ss == 3) ? 0.5f : 0.25f;
                pre0 = A1_0 + a * (md0 + c1_0) + bb1_0 + tcur * wt_0;
                pre1 = A1_1 + a * (md1 + c1_1) + bb1_1 + tcur * wt_1;
            }
            float h0 = tanhf(pre0), h1v = tanhf(pre1);
            u0 = 1.f - h0 * h0; u1 = 1.f - h1v * h1v;
            if (lane == 0) { ast(h1_g + gw2, h0); ast(h1_g + gw2 + 1, h1v); }
        }
        gbar(sync, b, ++g);

        // ================= Phase B: h2 = tanh(W2^T h1 + b2) =================
        #pragma unroll
        for (int q = 0; q < 8; ++q) {
            int i = t + (q << 8);
            vecH[i] = ald(h1_g + i);
        }
        __syncthreads();
        {
            float a0 = 0.f, a1 = 0.f;
            #pragma unroll
            for (int rep = 0; rep < 4; ++rep) {
                const int idx = rep * 512 + lane * 8;
                float4 hA = *(const float4*)(vecH + idx);
                float4 hB = *(const float4*)(vecH + idx + 4);
                float hv[8] = {hA.x, hA.y, hA.z, hA.w, hB.x, hB.y, hB.z, hB.w};
                short8 r0 = *(const short8*)&Qs[wib * 2][idx];
                short8 r1 = *(const short8*)&Qs[wib * 2 + 1][idx];
                #pragma unroll
                for (int e = 0; e < 8; ++e) {
                    a0 += b2f((unsigned short)r0[e]) * hv[e];
                    a1 += b2f((unsigned short)r1[e]) * hv[e];
                }
            }
            #pragma unroll
            for (int o = 1; o < 64; o <<= 1) {
                a0 += __shfl_xor(a0, o, 64); a1 += __shfl_xor(a1, o, 64);
            }
            float q0 = tanhf(a0 + bb2_0), q1 = tanhf(a1 + bb2_1);
            const float cs = (ss == 1 || ss == 2) ? (1.f / 6.f) : (1.f / 12.f);
            hc0 += cs * q0; hc1 += cs * q1;
            if (lane == 0) {
                ast(h2_g + gw2, q0); ast(h2_g + gw2 + 1, q1);
                if (ss == 3) { ast(hacc_g + gw2, hc0); ast(hacc_g + gw2 + 1, hc1); }
            }
        }
        gbar(sync, b, ++g);
    }

    // ================= Epilogue: last div + x_out; logq via divcnt poll =================
    {
        #pragma unroll
        for (int q = 0; q < 8; ++q) {
            int i = t + (q << 8);
            float h2v = ald(h2_g + i);
            vecH[i] = ald(hacc_g + i);
            vecW[i] = 1.f - h2v * h2v;
        }
        __syncthreads();
        float pd0 = 0.f, pd1 = 0.f, xo = 0.f;
        const unsigned short* Vr = W3T + (size_t)jx * HH;
        #pragma unroll
        for (int rep = 0; rep < 4; ++rep) {
            const int idx = rep * 512 + lane * 8;
            float4 cA = *(const float4*)(vecH + idx);
            float4 cB = *(const float4*)(vecH + idx + 4);
            float4 wA = *(const float4*)(vecW + idx);
            float4 wB = *(const float4*)(vecW + idx + 4);
            float cv[8] = {cA.x, cA.y, cA.z, cA.w, cB.x, cB.y, cB.z, cB.w};
            float wv[8] = {wA.x, wA.y, wA.z, wA.w, wB.x, wB.y, wB.z, wB.w};
            short8 p0v = *(const short8*)&Ps[wib * 2][idx];
            short8 p1v = *(const short8*)&Ps[wib * 2 + 1][idx];
            short8 vv = *(const short8*)(Vr + idx);
            #pragma unroll
            for (int e = 0; e < 8; ++e) {
                pd0 += b2f((unsigned short)p0v[e]) * wv[e];
                pd1 += b2f((unsigned short)p1v[e]) * wv[e];
                xo  += b2f((unsigned short)vv[e]) * cv[e];
            }
        }
        #pragma unroll
        for (int o = 1; o < 64; o <<= 1) {
            pd0 += __shfl_xor(pd0, o, 64); pd1 += __shfl_xor(pd1, o, 64);
            xo += __shfl_xor(xo, o, 64);
        }
        wdiv += (1.f / 12.f) * (u0 * pd0 + u1 * pd1);
        if (lane == 0) {
            out[jx] = x0[jx] + xo + b3[jx];
            wred[wib] = wdiv;
        }
    }
    __syncthreads();
    if (t == 0) {
        float dsum = wred[0] + wred[1] + wred[2] + wred[3];
        atomicAdd((float*)(sync + 4096 + (b & 15) * 16), dsum);
        asm volatile("s_waitcnt vmcnt(0)" ::: "memory");
        atomicAdd(sync + 4352, 1u);
    }
    if (b == 0 && wib == 0) {
        if (lane == 0) {
            while (__hip_atomic_load(sync + 4352, __ATOMIC_RELAXED, __HIP_MEMORY_SCOPE_AGENT) < NCB)
                __builtin_amdgcn_s_sleep(2);
        }
        float v = 0.f;
        if (lane < 16) {
            unsigned du = __hip_atomic_load(sync + 4096 + lane * 16,
                                            __ATOMIC_RELAXED, __HIP_MEMORY_SCOPE_AGENT);
            v = __uint_as_float(du);
        }
        #pragma unroll
        for (int o = 1; o < 64; o <<= 1) v += __shfl_xor(v, o, 64);
        if (lane == 0) out[DD] = logq_r - v;
    }
}

extern "C" void kernel_launch(void* const* d_in, const int* in_sizes, int n_in,
                              void* d_out, int out_size, void* d_ws, size_t ws_size,
                              hipStream_t stream) {
    const float* x0 = (const float*)d_in[0];
    const float* W1 = (const float*)d_in[1];
    const float* b1 = (const float*)d_in[2];
    const float* wt = (const float*)d_in[3];
    const float* W2 = (const float*)d_in[4];
    const float* b2 = (const float*)d_in[5];
    const float* W3 = (const float*)d_in[6];
    const float* b3 = (const float*)d_in[7];
    float* out = (float*)d_out;

    char* ws = (char*)d_ws;
    const size_t MB = 1024 * 1024;
    unsigned short* Pb  = (unsigned short*)(ws);            // 8 MB
    unsigned short* W2T = (unsigned short*)(ws + 8 * MB);   // 8 MB
    unsigned short* W3T = (unsigned short*)(ws + 16 * MB);  // 4 MB
    unsigned short* Mb  = (unsigned short*)(ws + 20 * MB);  // 8 MB
    float* fb = (float*)(ws + 28 * MB);
    float* c1      = fb;                       // 2048
    float* A1g     = fb + 2048;                // 2048
    float* h1_g    = fb + 4096;                // 2048
    float* h2_g    = fb + 6144;                // 2048
    float* hacc_g  = fb + 8192;                // 2048
    unsigned* sync = (unsigned*)(fb + 10240);  // 4368 uints

    k_gemmPT<<<1792, 256, 0, stream>>>(W1, W2, W3, b3, x0, Mb, Pb, W2T, W3T,
                                       c1, A1g, sync);
    k_chain<<<NCB, 256, 0, stream>>>(Mb, Pb, W2T, W3T, x0, b1, wt, b2, b3, c1, A1g,
                                     h1_g, h2_g, hacc_g, out, sync);
}

// Round 15
// 169.306 us; speedup vs baseline: 1.0465x; 1.0247x over previous
//
#include <hip/hip_runtime.h>
#include <math.h>

#define DD 1024
#define HH 2048
#define NCB 256

typedef float f32x4 __attribute__((ext_vector_type(4)));
typedef short short8 __attribute__((ext_vector_type(8)));

__device__ __forceinline__ float b2f(unsigned short u) {
    return __uint_as_float(((unsigned int)u) << 16);
}
__device__ __forceinline__ unsigned short f2b(float f) {
    unsigned int x = __float_as_uint(f);
    unsigned int r = (x + 0x7FFFu + ((x >> 16) & 1u)) >> 16;
    return (unsigned short)r;
}
__device__ __forceinline__ float ald(const float* p) {
    return __hip_atomic_load(p, __ATOMIC_RELAXED, __HIP_MEMORY_SCOPE_AGENT);
}
__device__ __forceinline__ void ast(float* p, float v) {
    __hip_atomic_store(p, v, __ATOMIC_RELAXED, __HIP_MEMORY_SCOPE_AGENT);
}

// ---------------- transposes only: [0,512) W1->W1T | [512,1536) W2->W2T | [1536,2048) W3->W3T
__global__ __launch_bounds__(256) void k_tr(const float* __restrict__ W1,
                                            const float* __restrict__ W2,
                                            const float* __restrict__ W3,
                                            unsigned short* __restrict__ W1T,
                                            unsigned short* __restrict__ W2T,
                                            unsigned short* __restrict__ W3T,
                                            unsigned* __restrict__ sync) {
    __shared__ float tile[64][65];
    const int b = blockIdx.x, t = threadIdx.x;
    if (b == 0) {
        #pragma unroll
        for (int q = 0; q < 18; ++q) {
            int i = t + q * 256;
            if (i < 4368) sync[i] = 0u;
        }
    }
    const float* in; unsigned short* out; int R, C, bx, by;
    if (b < 512)       { int bb = b;        in = W1; out = W1T; R = DD; C = HH; bx = bb & 31; by = bb >> 5; }
    else if (b < 1536) { int bb = b - 512;  in = W2; out = W2T; R = HH; C = HH; bx = bb & 31; by = bb >> 5; }
    else               { int bb = b - 1536; in = W3; out = W3T; R = HH; C = DD; bx = bb & 15; by = bb >> 4; }
    const int c0 = bx * 64, r0 = by * 64;
    const int cc = t & 63, rb = t >> 6;
    #pragma unroll
    for (int p = 0; p < 16; ++p) {
        int rr = p * 4 + rb;
        tile[rr][cc] = in[(size_t)(r0 + rr) * C + c0 + cc];
    }
    __syncthreads();
    #pragma unroll
    for (int p = 0; p < 16; ++p) {
        int rr = p * 4 + rb;
        out[(size_t)(c0 + rr) * R + r0 + cc] = f2b(tile[cc][rr]);
    }
}

// ---------------- M = W1^T W3^T, P = M .* W2, c1 = W1^T b3, A1 = W1^T x0 ----------------
__global__ __launch_bounds__(256) void k_gemmP(const unsigned short* __restrict__ W1T,
                                               const float* __restrict__ W3,
                                               const float* __restrict__ W2,
                                               const float* __restrict__ b3,
                                               const float* __restrict__ x0,
                                               unsigned short* __restrict__ Mb,
                                               unsigned short* __restrict__ Pb,
                                               float* __restrict__ c1,
                                               float* __restrict__ A1g) {
    __shared__ unsigned short At[128][40];
    __shared__ unsigned short Bt[128][40];
    const int b = blockIdx.x, t = threadIdx.x;
    const int m0 = (b & 15) * 128;   // same-m0 blocks land on one XCD (16 = 0 mod 8)
    const int k0 = (b >> 4) * 128;
    const int r = t & 127, half = t >> 7;
    const int wv = t >> 6, l = t & 63;
    const int wr = wv >> 1, wc = wv & 1;
    const int fr = l & 15, fg = l >> 4;
    const bool do_aux = ((b >> 4) == 0) && (t < 128);
    float c1acc = 0.f, a1acc = 0.f;

    f32x4 acc[4][4] = {};
    for (int i0 = 0; i0 < DD; i0 += 32) {
        {
            const float4* sa = (const float4*)(W1T + (size_t)(m0 + r) * DD + i0 + half * 16);
            float4 a0 = sa[0], a1 = sa[1];
            float4* da = (float4*)&At[r][half * 16];
            da[0] = a0; da[1] = a1;
        }
        {
            const float4* sbf = (const float4*)(W3 + (size_t)(k0 + r) * DD + i0 + half * 16);
            float4 f0 = sbf[0], f1 = sbf[1], f2v = sbf[2], f3 = sbf[3];
            short8 o0, o1;
            o0[0] = (short)f2b(f0.x); o0[1] = (short)f2b(f0.y); o0[2] = (short)f2b(f0.z); o0[3] = (short)f2b(f0.w);
            o0[4] = (short)f2b(f1.x); o0[5] = (short)f2b(f1.y); o0[6] = (short)f2b(f1.z); o0[7] = (short)f2b(f1.w);
            o1[0] = (short)f2b(f2v.x); o1[1] = (short)f2b(f2v.y); o1[2] = (short)f2b(f2v.z); o1[3] = (short)f2b(f2v.w);
            o1[4] = (short)f2b(f3.x); o1[5] = (short)f2b(f3.y); o1[6] = (short)f2b(f3.z); o1[7] = (short)f2b(f3.w);
            *(short8*)&Bt[r][half * 16] = o0;
            *(short8*)&Bt[r][half * 16 + 8] = o1;
        }
        __syncthreads();
        if (do_aux) {
            #pragma unroll
            for (int i = 0; i < 32; ++i) {
                float w1v = b2f(At[t][i]);
                c1acc += w1v * b3[i0 + i];
                a1acc += w1v * x0[i0 + i];
            }
        }
        short8 af[4], bf[4];
        #pragma unroll
        for (int a = 0; a < 4; ++a)
            af[a] = *(const short8*)&At[wr * 64 + a * 16 + fr][fg * 8];
        #pragma unroll
        for (int bq = 0; bq < 4; ++bq)
            bf[bq] = *(const short8*)&Bt[wc * 64 + bq * 16 + fr][fg * 8];
        #pragma unroll
        for (int a = 0; a < 4; ++a)
            #pragma unroll
            for (int bq = 0; bq < 4; ++bq)
                acc[a][bq] = __builtin_amdgcn_mfma_f32_16x16x32_bf16(af[a], bf[bq], acc[a][bq], 0, 0, 0);
        __syncthreads();
    }
    if (do_aux) { c1[m0 + t] = c1acc; A1g[m0 + t] = a1acc; }
    #pragma unroll
    for (int a = 0; a < 4; ++a) {
        #pragma unroll
        for (int bq = 0; bq < 4; ++bq) {
            #pragma unroll
            for (int j = 0; j < 4; ++j) {
                int row = m0 + wr * 64 + a * 16 + fg * 4 + j;
                int col = k0 + wc * 64 + bq * 16 + fr;
                size_t idx = (size_t)row * HH + col;
                float m = acc[a][bq][j];
                Mb[idx] = f2b(m);
                Pb[idx] = f2b(m * W2[idx]);
            }
        }
    }
}

// ---------------- direct-scan grid barrier (agent scope) ----------------
__device__ __forceinline__ void gbar(unsigned* sync, int b, unsigned g) {
    __syncthreads();
    if (threadIdx.x < 64) {
        if (threadIdx.x == 0) {
            asm volatile("s_waitcnt vmcnt(0)" ::: "memory");
            __hip_atomic_store(&sync[b << 4], g, __ATOMIC_RELAXED, __HIP_MEMORY_SCOPE_AGENT);
        }
        while (true) {
            bool ok = true;
            #pragma unroll
            for (int k = 0; k < 4; ++k) {
                unsigned f = __hip_atomic_load(&sync[(threadIdx.x + (k << 6)) << 4],
                                               __ATOMIC_RELAXED, __HIP_MEMORY_SCOPE_AGENT);
                ok &= (f >= g);
            }
            if (!__any((int)(!ok))) break;
            __builtin_amdgcn_s_sleep(1);
        }
    }
    __syncthreads();
}

// ---------------- persistent RK4 chain (identical to R14) ----------------
__global__ __launch_bounds__(256, 1) void k_chain(
    const unsigned short* __restrict__ Mb,
    const unsigned short* __restrict__ Pb,
    const unsigned short* __restrict__ W2T,
    const unsigned short* __restrict__ W3T,
    const float* __restrict__ x0,
    const float* __restrict__ b1, const float* __restrict__ wt,
    const float* __restrict__ b2, const float* __restrict__ b3,
    const float* __restrict__ c1, const float* __restrict__ A1g,
    float* __restrict__ h1_g, float* __restrict__ h2_g, float* __restrict__ hacc_g,
    float* __restrict__ out,
    unsigned* __restrict__ sync) {
    __shared__ unsigned short Ms[8][2048];
    __shared__ unsigned short Ps[8][2048];
    __shared__ unsigned short Qs[8][2048];
    __shared__ float vecH[2048];
    __shared__ float vecW[2048];
    __shared__ float wred[4];
    const int t = threadIdx.x, b = blockIdx.x;
    const int wib = t >> 6, lane = t & 63;
    const int gw2 = (b << 3) + (wib << 1);
    const int jx = (b << 2) + wib;
    unsigned g = 0;

    {
        const unsigned short* mp = Mb + (size_t)gw2 * HH;
        const unsigned short* pp = Pb + (size_t)gw2 * HH;
        const unsigned short* qp = W2T + (size_t)gw2 * HH;
        #pragma unroll
        for (int rep = 0; rep < 4; ++rep) {
            const int idx = rep * 512 + lane * 8;
            *(short8*)&Ms[wib * 2][idx]     = *(const short8*)(mp + idx);
            *(short8*)&Ms[wib * 2 + 1][idx] = *(const short8*)(mp + HH + idx);
            *(short8*)&Ps[wib * 2][idx]     = *(const short8*)(pp + idx);
            *(short8*)&Ps[wib * 2 + 1][idx] = *(const short8*)(pp + HH + idx);
            *(short8*)&Qs[wib * 2][idx]     = *(const short8*)(qp + idx);
            *(short8*)&Qs[wib * 2 + 1][idx] = *(const short8*)(qp + HH + idx);
        }
    }

    const float bb1_0 = b1[gw2], bb1_1 = b1[gw2 + 1];
    const float wt_0 = wt[gw2], wt_1 = wt[gw2 + 1];
    const float bb2_0 = b2[gw2], bb2_1 = b2[gw2 + 1];
    const float c1_0 = c1[gw2], c1_1 = c1[gw2 + 1];

    float A1_0 = 0.f, A1_1 = 0.f;
    float u0 = 0.f, u1 = 0.f;
    float hc0 = 0.f, hc1 = 0.f;
    float wdiv = 0.f;

    float logq_r = 0.f;
    if (b == 0 && wib == 0) {
        float ssum = 0.f;
        #pragma unroll
        for (int q = 0; q < 16; ++q) { float xv = x0[lane + (q << 6)]; ssum += xv * xv; }
        #pragma unroll
        for (int o = 1; o < 64; o <<= 1) ssum += __shfl_xor(ssum, o, 64);
        logq_r = -0.5f * ssum - 0.5f * 1024.0f * 1.8378770664093453f;
    }

    for (int s = 0; s < 8; ++s) {
        const int ss = s & 3;
        const float tcur = (s >> 2) * 0.5f + ((ss == 0) ? 0.f : (ss == 3) ? 0.5f : 0.25f);

        // ================= Phase A =================
        if (s == 0) {
            A1_0 = A1g[gw2]; A1_1 = A1g[gw2 + 1];
            float h0 = tanhf(A1_0 + bb1_0 + tcur * wt_0);
            float h1v = tanhf(A1_1 + bb1_1 + tcur * wt_1);
            u0 = 1.f - h0 * h0; u1 = 1.f - h1v * h1v;
            if (lane == 0) { ast(h1_g + gw2, h0); ast(h1_g + gw2 + 1, h1v); }
        } else {
            #pragma unroll
            for (int q = 0; q < 8; ++q) {
                int i = t + (q << 8);
                float h2v = ald(h2_g + i);
                float sv = (ss == 0) ? ald(hacc_g + i) : h2v;
                vecH[i] = sv;
                vecW[i] = 1.f - h2v * h2v;
            }
            __syncthreads();
            float md0 = 0.f, md1 = 0.f, pd0 = 0.f, pd1 = 0.f;
            #pragma unroll
            for (int rep = 0; rep < 4; ++rep) {
                const int idx = rep * 512 + lane * 8;
                float4 hA = *(const float4*)(vecH + idx);
                float4 hB = *(const float4*)(vecH + idx + 4);
                float4 wA = *(const float4*)(vecW + idx);
                float4 wB = *(const float4*)(vecW + idx + 4);
                float hv[8] = {hA.x, hA.y, hA.z, hA.w, hB.x, hB.y, hB.z, hB.w};
                float wv[8] = {wA.x, wA.y, wA.z, wA.w, wB.x, wB.y, wB.z, wB.w};
                short8 m0v = *(const short8*)&Ms[wib * 2][idx];
                short8 m1v = *(const short8*)&Ms[wib * 2 + 1][idx];
                short8 p0v = *(const short8*)&Ps[wib * 2][idx];
                short8 p1v = *(const short8*)&Ps[wib * 2 + 1][idx];
                #pragma unroll
                for (int e = 0; e < 8; ++e) {
                    md0 += b2f((unsigned short)m0v[e]) * hv[e];
                    md1 += b2f((unsigned short)m1v[e]) * hv[e];
                    pd0 += b2f((unsigned short)p0v[e]) * wv[e];
                    pd1 += b2f((unsigned short)p1v[e]) * wv[e];
                }
            }
            #pragma unroll
            for (int o = 1; o < 64; o <<= 1) {
                md0 += __shfl_xor(md0, o, 64); md1 += __shfl_xor(md1, o, 64);
                pd0 += __shfl_xor(pd0, o, 64); pd1 += __shfl_xor(pd1, o, 64);
            }
            const int sp = (s - 1) & 3;
            const float cprev = (sp == 1 || sp == 2) ? (1.f / 6.f) : (1.f / 12.f);
            wdiv += cprev * (u0 * pd0 + u1 * pd1);
            float pre0, pre1;
            if (ss == 0) {
                A1_0 += md0 + 0.5f * c1_0; A1_1 += md1 + 0.5f * c1_1;
                pre0 = A1_0 + bb1_0 + tcur * wt_0; pre1 = A1_1 + bb1_1 + tcur * wt_1;
            } else {
                const float a = (ss == 3) ? 0.5f : 0.25f;
                pre0 = A1_0 + a * (md0 + c1_0) + bb1_0 + tcur * wt_0;
                pre1 = A1_1 + a * (md1 + c1_1) + bb1_1 + tcur * wt_1;
            }
            float h0 = tanhf(pre0), h1v = tanhf(pre1);
            u0 = 1.f - h0 * h0; u1 = 1.f - h1v * h1v;
            if (lane == 0) { ast(h1_g + gw2, h0); ast(h1_g + gw2 + 1, h1v); }
        }
        gbar(sync, b, ++g);

        // ================= Phase B =================
        #pragma unroll
        for (int q = 0; q < 8; ++q) {
            int i = t + (q << 8);
            vecH[i] = ald(h1_g + i);
        }
        __syncthreads();
        {
            float a0 = 0.f, a1 = 0.f;
            #pragma unroll
            for (int rep = 0; rep < 4; ++rep) {
                const int idx = rep * 512 + lane * 8;
                float4 hA = *(const float4*)(vecH + idx);
                float4 hB = *(const float4*)(vecH + idx + 4);
                float hv[8] = {hA.x, hA.y, hA.z, hA.w, hB.x, hB.y, hB.z, hB.w};
                short8 r0 = *(const short8*)&Qs[wib * 2][idx];
                short8 r1 = *(const short8*)&Qs[wib * 2 + 1][idx];
                #pragma unroll
                for (int e = 0; e < 8; ++e) {
                    a0 += b2f((unsigned short)r0[e]) * hv[e];
                    a1 += b2f((unsigned short)r1[e]) * hv[e];
                }
            }
            #pragma unroll
            for (int o = 1; o < 64; o <<= 1) {
                a0 += __shfl_xor(a0, o, 64); a1 += __shfl_xor(a1, o, 64);
            }
            float q0 = tanhf(a0 + bb2_0), q1 = tanhf(a1 + bb2_1);
            const float cs = (ss == 1 || ss == 2) ? (1.f / 6.f) : (1.f / 12.f);
            hc0 += cs * q0; hc1 += cs * q1;
            if (lane == 0) {
                ast(h2_g + gw2, q0); ast(h2_g + gw2 + 1, q1);
                if (ss == 3) { ast(hacc_g + gw2, hc0); ast(hacc_g + gw2 + 1, hc1); }
            }
        }
        gbar(sync, b, ++g);
    }

    // ================= Epilogue =================
    {
        #pragma unroll
        for (int q = 0; q < 8; ++q) {
            int i = t + (q << 8);
            float h2v = ald(h2_g + i);
            vecH[i] = ald(hacc_g + i);
            vecW[i] = 1.f - h2v * h2v;
        }
        __syncthreads();
        float pd0 = 0.f, pd1 = 0.f, xo = 0.f;
        const unsigned short* Vr = W3T + (size_t)jx * HH;
        #pragma unroll
        for (int rep = 0; rep < 4; ++rep) {
            const int idx = rep * 512 + lane * 8;
            float4 cA = *(const float4*)(vecH + idx);
            float4 cB = *(const float4*)(vecH + idx + 4);
            float4 wA = *(const float4*)(vecW + idx);
            float4 wB = *(const float4*)(vecW + idx + 4);
            float cv[8] = {cA.x, cA.y, cA.z, cA.w, cB.x, cB.y, cB.z, cB.w};
            float wv[8] = {wA.x, wA.y, wA.z, wA.w, wB.x, wB.y, wB.z, wB.w};
            short8 p0v = *(const short8*)&Ps[wib * 2][idx];
            short8 p1v = *(const short8*)&Ps[wib * 2 + 1][idx];
            short8 vv = *(const short8*)(Vr + idx);
            #pragma unroll
            for (int e = 0; e < 8; ++e) {
                pd0 += b2f((unsigned short)p0v[e]) * wv[e];
                pd1 += b2f((unsigned short)p1v[e]) * wv[e];
                xo  += b2f((unsigned short)vv[e]) * cv[e];
            }
        }
        #pragma unroll
        for (int o = 1; o < 64; o <<= 1) {
            pd0 += __shfl_xor(pd0, o, 64); pd1 += __shfl_xor(pd1, o, 64);
            xo += __shfl_xor(xo, o, 64);
        }
        wdiv += (1.f / 12.f) * (u0 * pd0 + u1 * pd1);
        if (lane == 0) {
            out[jx] = x0[jx] + xo + b3[jx];
            wred[wib] = wdiv;
        }
    }
    __syncthreads();
    if (t == 0) {
        float dsum = wred[0] + wred[1] + wred[2] + wred[3];
        atomicAdd((float*)(sync + 4096 + (b & 15) * 16), dsum);
        asm volatile("s_waitcnt vmcnt(0)" ::: "memory");
        atomicAdd(sync + 4352, 1u);
    }
    if (b == 0 && wib == 0) {
        if (lane == 0) {
            while (__hip_atomic_load(sync + 4352, __ATOMIC_RELAXED, __HIP_MEMORY_SCOPE_AGENT) < NCB)
                __builtin_amdgcn_s_sleep(2);
        }
        float v = 0.f;
        if (lane < 16) {
            unsigned du = __hip_atomic_load(sync + 4096 + lane * 16,
                                            __ATOMIC_RELAXED, __HIP_MEMORY_SCOPE_AGENT);
            v = __uint_as_float(du);
        }
        #pragma unroll
        for (int o = 1; o < 64; o <<= 1) v += __shfl_xor(v, o, 64);
        if (lane == 0) out[DD] = logq_r - v;
    }
}

extern "C" void kernel_launch(void* const* d_in, const int* in_sizes, int n_in,
                              void* d_out, int out_size, void* d_ws, size_t ws_size,
                              hipStream_t stream) {
    const float* x0 = (const float*)d_in[0];
    const float* W1 = (const float*)d_in[1];
    const float* b1 = (const float*)d_in[2];
    const float* wt = (const float*)d_in[3];
    const float* W2 = (const float*)d_in[4];
    const float* b2 = (const float*)d_in[5];
    const float* W3 = (const float*)d_in[6];
    const float* b3 = (const float*)d_in[7];
    float* out = (float*)d_out;

    char* ws = (char*)d_ws;
    const size_t MB = 1024 * 1024;
    unsigned short* Pb  = (unsigned short*)(ws);            // 8 MB
    unsigned short* W2T = (unsigned short*)(ws + 8 * MB);   // 8 MB
    unsigned short* W3T = (unsigned short*)(ws + 16 * MB);  // 4 MB
    unsigned short* Mb  = (unsigned short*)(ws + 20 * MB);  // 8 MB
    unsigned short* W1T = (unsigned short*)(ws + 28 * MB);  // 4 MB
    float* fb = (float*)(ws + 32 * MB);
    float* c1      = fb;                       // 2048
    float* A1g     = fb + 2048;                // 2048
    float* h1_g    = fb + 4096;                // 2048
    float* h2_g    = fb + 6144;                // 2048
    float* hacc_g  = fb + 8192;                // 2048
    unsigned* sync = (unsigned*)(fb + 10240);  // 4368 uints

    k_tr<<<2048, 256, 0, stream>>>(W1, W2, W3, W1T, W2T, W3T, sync);
    k_gemmP<<<256, 256, 0, stream>>>(W1T, W3, W2, b3, x0, Mb, Pb, c1, A1g);
    k_chain<<<NCB, 256, 0, stream>>>(Mb, Pb, W2T, W3T, x0, b1, wt, b2, b3, c1, A1g,
                                     h1_g, h2_g, hacc_g, out, sync);
}

// Round 16
// 164.549 us; speedup vs baseline: 1.0767x; 1.0289x over previous
//
#include <hip/hip_runtime.h>
#include <math.h>

#define DD 1024
#define HH 2048
#define NCB 256

typedef float f32x4 __attribute__((ext_vector_type(4)));
typedef short short8 __attribute__((ext_vector_type(8)));

__device__ __forceinline__ float b2f(unsigned short u) {
    return __uint_as_float(((unsigned int)u) << 16);
}
__device__ __forceinline__ unsigned short f2b(float f) {
    unsigned int x = __float_as_uint(f);
    unsigned int r = (x + 0x7FFFu + ((x >> 16) & 1u)) >> 16;
    return (unsigned short)r;
}
__device__ __forceinline__ float ald(const float* p) {
    return __hip_atomic_load(p, __ATOMIC_RELAXED, __HIP_MEMORY_SCOPE_AGENT);
}
__device__ __forceinline__ void ast(float* p, float v) {
    __hip_atomic_store(p, v, __ATOMIC_RELAXED, __HIP_MEMORY_SCOPE_AGENT);
}

// ---------------- transposes: [0,512) W1T | [512,1536) W2T | [1536,2048) W3T + W3b ----------------
__global__ __launch_bounds__(256) void k_tr(const float* __restrict__ W1,
                                            const float* __restrict__ W2,
                                            const float* __restrict__ W3,
                                            unsigned short* __restrict__ W1T,
                                            unsigned short* __restrict__ W2T,
                                            unsigned short* __restrict__ W3T,
                                            unsigned short* __restrict__ W3b,
                                            unsigned* __restrict__ sync) {
    __shared__ float tile[64][65];
    const int b = blockIdx.x, t = threadIdx.x;
    if (b == 0) {
        #pragma unroll
        for (int q = 0; q < 18; ++q) {
            int i = t + q * 256;
            if (i < 4368) sync[i] = 0u;
        }
    }
    const float* in; unsigned short* out; int R, C, bx, by;
    bool isW3 = false;
    if (b < 512)       { int bb = b;        in = W1; out = W1T; R = DD; C = HH; bx = bb & 31; by = bb >> 5; }
    else if (b < 1536) { int bb = b - 512;  in = W2; out = W2T; R = HH; C = HH; bx = bb & 31; by = bb >> 5; }
    else               { int bb = b - 1536; in = W3; out = W3T; R = HH; C = DD; bx = bb & 15; by = bb >> 4; isW3 = true; }
    const int c0 = bx * 64, r0 = by * 64;
    const int cc = t & 63, rb = t >> 6;
    #pragma unroll
    for (int p = 0; p < 16; ++p) {
        int rr = p * 4 + rb;
        float v = in[(size_t)(r0 + rr) * C + c0 + cc];
        tile[rr][cc] = v;
        if (isW3) W3b[(size_t)(r0 + rr) * DD + c0 + cc] = f2b(v);
    }
    __syncthreads();
    #pragma unroll
    for (int p = 0; p < 16; ++p) {
        int rr = p * 4 + rb;
        out[(size_t)(c0 + rr) * R + r0 + cc] = f2b(tile[cc][rr]);
    }
}

// ---------------- M = W1^T W3^T, P = M .* W2, c1 = W1^T b3, A1 = W1^T x0 (all-bf16 staging) ----------------
__global__ __launch_bounds__(256) void k_gemmP(const unsigned short* __restrict__ W1T,
                                               const unsigned short* __restrict__ W3b,
                                               const float* __restrict__ W2,
                                               const float* __restrict__ b3,
                                               const float* __restrict__ x0,
                                               unsigned short* __restrict__ Mb,
                                               unsigned short* __restrict__ Pb,
                                               float* __restrict__ c1,
                                               float* __restrict__ A1g) {
    __shared__ unsigned short At[128][40];
    __shared__ unsigned short Bt[128][40];
    const int b = blockIdx.x, t = threadIdx.x;
    const int m0 = (b & 15) * 128;   // same-m0 blocks cluster on one XCD
    const int k0 = (b >> 4) * 128;
    const int r = t & 127, half = t >> 7;
    const int wv = t >> 6, l = t & 63;
    const int wr = wv >> 1, wc = wv & 1;
    const int fr = l & 15, fg = l >> 4;
    const bool do_aux = ((b >> 4) == 0) && (t < 128);
    float c1acc = 0.f, a1acc = 0.f;

    f32x4 acc[4][4] = {};
    for (int i0 = 0; i0 < DD; i0 += 32) {
        {
            const float4* sa = (const float4*)(W1T + (size_t)(m0 + r) * DD + i0 + half * 16);
            const float4* sb = (const float4*)(W3b + (size_t)(k0 + r) * DD + i0 + half * 16);
            float4 a0 = sa[0], a1 = sa[1];
            float4 b0 = sb[0], b1 = sb[1];
            float4* da = (float4*)&At[r][half * 16];
            float4* db = (float4*)&Bt[r][half * 16];
            da[0] = a0; da[1] = a1;
            db[0] = b0; db[1] = b1;
        }
        __syncthreads();
        if (do_aux) {
            #pragma unroll
            for (int i = 0; i < 32; ++i) {
                float w1v = b2f(At[t][i]);
                c1acc += w1v * b3[i0 + i];
                a1acc += w1v * x0[i0 + i];
            }
        }
        short8 af[4], bf[4];
        #pragma unroll
        for (int a = 0; a < 4; ++a)
            af[a] = *(const short8*)&At[wr * 64 + a * 16 + fr][fg * 8];
        #pragma unroll
        for (int bq = 0; bq < 4; ++bq)
            bf[bq] = *(const short8*)&Bt[wc * 64 + bq * 16 + fr][fg * 8];
        #pragma unroll
        for (int a = 0; a < 4; ++a)
            #pragma unroll
            for (int bq = 0; bq < 4; ++bq)
                acc[a][bq] = __builtin_amdgcn_mfma_f32_16x16x32_bf16(af[a], bf[bq], acc[a][bq], 0, 0, 0);
        __syncthreads();
    }
    if (do_aux) { c1[m0 + t] = c1acc; A1g[m0 + t] = a1acc; }
    #pragma unroll
    for (int a = 0; a < 4; ++a) {
        #pragma unroll
        for (int bq = 0; bq < 4; ++bq) {
            #pragma unroll
            for (int j = 0; j < 4; ++j) {
                int row = m0 + wr * 64 + a * 16 + fg * 4 + j;
                int col = k0 + wc * 64 + bq * 16 + fr;
                size_t idx = (size_t)row * HH + col;
                float m = acc[a][bq][j];
                Mb[idx] = f2b(m);
                Pb[idx] = f2b(m * W2[idx]);
            }
        }
    }
}

// ---------------- direct-scan grid barrier (agent scope) ----------------
__device__ __forceinline__ void gbar(unsigned* sync, int b, unsigned g) {
    __syncthreads();
    if (threadIdx.x < 64) {
        if (threadIdx.x == 0) {
            asm volatile("s_waitcnt vmcnt(0)" ::: "memory");
            __hip_atomic_store(&sync[b << 4], g, __ATOMIC_RELAXED, __HIP_MEMORY_SCOPE_AGENT);
        }
        while (true) {
            bool ok = true;
            #pragma unroll
            for (int k = 0; k < 4; ++k) {
                unsigned f = __hip_atomic_load(&sync[(threadIdx.x + (k << 6)) << 4],
                                               __ATOMIC_RELAXED, __HIP_MEMORY_SCOPE_AGENT);
                ok &= (f >= g);
            }
            if (!__any((int)(!ok))) break;
            __builtin_amdgcn_s_sleep(1);
        }
    }
    __syncthreads();
}

// ---------------- persistent RK4 chain (identical to R14/R15) ----------------
__global__ __launch_bounds__(256, 1) void k_chain(
    const unsigned short* __restrict__ Mb,
    const unsigned short* __restrict__ Pb,
    const unsigned short* __restrict__ W2T,
    const unsigned short* __restrict__ W3T,
    const float* __restrict__ x0,
    const float* __restrict__ b1, const float* __restrict__ wt,
    const float* __restrict__ b2, const float* __restrict__ b3,
    const float* __restrict__ c1, const float* __restrict__ A1g,
    float* __restrict__ h1_g, float* __restrict__ h2_g, float* __restrict__ hacc_g,
    float* __restrict__ out,
    unsigned* __restrict__ sync) {
    __shared__ unsigned short Ms[8][2048];
    __shared__ unsigned short Ps[8][2048];
    __shared__ unsigned short Qs[8][2048];
    __shared__ float vecH[2048];
    __shared__ float vecW[2048];
    __shared__ float wred[4];
    const int t = threadIdx.x, b = blockIdx.x;
    const int wib = t >> 6, lane = t & 63;
    const int gw2 = (b << 3) + (wib << 1);
    const int jx = (b << 2) + wib;
    unsigned g = 0;

    {
        const unsigned short* mp = Mb + (size_t)gw2 * HH;
        const unsigned short* pp = Pb + (size_t)gw2 * HH;
        const unsigned short* qp = W2T + (size_t)gw2 * HH;
        #pragma unroll
        for (int rep = 0; rep < 4; ++rep) {
            const int idx = rep * 512 + lane * 8;
            *(short8*)&Ms[wib * 2][idx]     = *(const short8*)(mp + idx);
            *(short8*)&Ms[wib * 2 + 1][idx] = *(const short8*)(mp + HH + idx);
            *(short8*)&Ps[wib * 2][idx]     = *(const short8*)(pp + idx);
            *(short8*)&Ps[wib * 2 + 1][idx] = *(const short8*)(pp + HH + idx);
            *(short8*)&Qs[wib * 2][idx]     = *(const short8*)(qp + idx);
            *(short8*)&Qs[wib * 2 + 1][idx] = *(const short8*)(qp + HH + idx);
        }
    }

    const float bb1_0 = b1[gw2], bb1_1 = b1[gw2 + 1];
    const float wt_0 = wt[gw2], wt_1 = wt[gw2 + 1];
    const float bb2_0 = b2[gw2], bb2_1 = b2[gw2 + 1];
    const float c1_0 = c1[gw2], c1_1 = c1[gw2 + 1];

    float A1_0 = 0.f, A1_1 = 0.f;
    float u0 = 0.f, u1 = 0.f;
    float hc0 = 0.f, hc1 = 0.f;
    float wdiv = 0.f;

    float logq_r = 0.f;
    if (b == 0 && wib == 0) {
        float ssum = 0.f;
        #pragma unroll
        for (int q = 0; q < 16; ++q) { float xv = x0[lane + (q << 6)]; ssum += xv * xv; }
        #pragma unroll
        for (int o = 1; o < 64; o <<= 1) ssum += __shfl_xor(ssum, o, 64);
        logq_r = -0.5f * ssum - 0.5f * 1024.0f * 1.8378770664093453f;
    }

    for (int s = 0; s < 8; ++s) {
        const int ss = s & 3;
        const float tcur = (s >> 2) * 0.5f + ((ss == 0) ? 0.f : (ss == 3) ? 0.5f : 0.25f);

        // ================= Phase A =================
        if (s == 0) {
            A1_0 = A1g[gw2]; A1_1 = A1g[gw2 + 1];
            float h0 = tanhf(A1_0 + bb1_0 + tcur * wt_0);
            float h1v = tanhf(A1_1 + bb1_1 + tcur * wt_1);
            u0 = 1.f - h0 * h0; u1 = 1.f - h1v * h1v;
            if (lane == 0) { ast(h1_g + gw2, h0); ast(h1_g + gw2 + 1, h1v); }
        } else {
            #pragma unroll
            for (int q = 0; q < 8; ++q) {
                int i = t + (q << 8);
                float h2v = ald(h2_g + i);
                float sv = (ss == 0) ? ald(hacc_g + i) : h2v;
                vecH[i] = sv;
                vecW[i] = 1.f - h2v * h2v;
            }
            __syncthreads();
            float md0 = 0.f, md1 = 0.f, pd0 = 0.f, pd1 = 0.f;
            #pragma unroll
            for (int rep = 0; rep < 4; ++rep) {
                const int idx = rep * 512 + lane * 8;
                float4 hA = *(const float4*)(vecH + idx);
                float4 hB = *(const float4*)(vecH + idx + 4);
                float4 wA = *(const float4*)(vecW + idx);
                float4 wB = *(const float4*)(vecW + idx + 4);
                float hv[8] = {hA.x, hA.y, hA.z, hA.w, hB.x, hB.y, hB.z, hB.w};
                float wv[8] = {wA.x, wA.y, wA.z, wA.w, wB.x, wB.y, wB.z, wB.w};
                short8 m0v = *(const short8*)&Ms[wib * 2][idx];
                short8 m1v = *(const short8*)&Ms[wib * 2 + 1][idx];
                short8 p0v = *(const short8*)&Ps[wib * 2][idx];
                short8 p1v = *(const short8*)&Ps[wib * 2 + 1][idx];
                #pragma unroll
                for (int e = 0; e < 8; ++e) {
                    md0 += b2f((unsigned short)m0v[e]) * hv[e];
                    md1 += b2f((unsigned short)m1v[e]) * hv[e];
                    pd0 += b2f((unsigned short)p0v[e]) * wv[e];
                    pd1 += b2f((unsigned short)p1v[e]) * wv[e];
                }
            }
            #pragma unroll
            for (int o = 1; o < 64; o <<= 1) {
                md0 += __shfl_xor(md0, o, 64); md1 += __shfl_xor(md1, o, 64);
                pd0 += __shfl_xor(pd0, o, 64); pd1 += __shfl_xor(pd1, o, 64);
            }
            const int sp = (s - 1) & 3;
            const float cprev = (sp == 1 || sp == 2) ? (1.f / 6.f) : (1.f / 12.f);
            wdiv += cprev * (u0 * pd0 + u1 * pd1);
            float pre0, pre1;
            if (ss == 0) {
                A1_0 += md0 + 0.5f * c1_0; A1_1 += md1 + 0.5f * c1_1;
                pre0 = A1_0 + bb1_0 + tcur * wt_0; pre1 = A1_1 + bb1_1 + tcur * wt_1;
            } else {
                const float a = (ss == 3) ? 0.5f : 0.25f;
                pre0 = A1_0 + a * (md0 + c1_0) + bb1_0 + tcur * wt_0;
                pre1 = A1_1 + a * (md1 + c1_1) + bb1_1 + tcur * wt_1;
            }
            float h0 = tanhf(pre0), h1v = tanhf(pre1);
            u0 = 1.f - h0 * h0; u1 = 1.f - h1v * h1v;
            if (lane == 0) { ast(h1_g + gw2, h0); ast(h1_g + gw2 + 1, h1v); }
        }
        gbar(sync, b, ++g);

        // ================= Phase B =================
        #pragma unroll
        for (int q = 0; q < 8; ++q) {
            int i = t + (q << 8);
            vecH[i] = ald(h1_g + i);
        }
        __syncthreads();
        {
            float a0 = 0.f, a1 = 0.f;
            #pragma unroll
            for (int rep = 0; rep < 4; ++rep) {
                const int idx = rep * 512 + lane * 8;
                float4 hA = *(const float4*)(vecH + idx);
                float4 hB = *(const float4*)(vecH + idx + 4);
                float hv[8] = {hA.x, hA.y, hA.z, hA.w, hB.x, hB.y, hB.z, hB.w};
                short8 r0 = *(const short8*)&Qs[wib * 2][idx];
                short8 r1 = *(const short8*)&Qs[wib * 2 + 1][idx];
                #pragma unroll
                for (int e = 0; e < 8; ++e) {
                    a0 += b2f((unsigned short)r0[e]) * hv[e];
                    a1 += b2f((unsigned short)r1[e]) * hv[e];
                }
            }
            #pragma unroll
            for (int o = 1; o < 64; o <<= 1) {
                a0 += __shfl_xor(a0, o, 64); a1 += __shfl_xor(a1, o, 64);
            }
            float q0 = tanhf(a0 + bb2_0), q1 = tanhf(a1 + bb2_1);
            const float cs = (ss == 1 || ss == 2) ? (1.f / 6.f) : (1.f / 12.f);
            hc0 += cs * q0; hc1 += cs * q1;
            if (lane == 0) {
                ast(h2_g + gw2, q0); ast(h2_g + gw2 + 1, q1);
                if (ss == 3) { ast(hacc_g + gw2, hc0); ast(hacc_g + gw2 + 1, hc1); }
            }
        }
        gbar(sync, b, ++g);
    }

    // ================= Epilogue =================
    {
        #pragma unroll
        for (int q = 0; q < 8; ++q) {
            int i = t + (q << 8);
            float h2v = ald(h2_g + i);
            vecH[i] = ald(hacc_g + i);
            vecW[i] = 1.f - h2v * h2v;
        }
        __syncthreads();
        float pd0 = 0.f, pd1 = 0.f, xo = 0.f;
        const unsigned short* Vr = W3T + (size_t)jx * HH;
        #pragma unroll
        for (int rep = 0; rep < 4; ++rep) {
            const int idx = rep * 512 + lane * 8;
            float4 cA = *(const float4*)(vecH + idx);
            float4 cB = *(const float4*)(vecH + idx + 4);
            float4 wA = *(const float4*)(vecW + idx);
            float4 wB = *(const float4*)(vecW + idx + 4);
            float cv[8] = {cA.x, cA.y, cA.z, cA.w, cB.x, cB.y, cB.z, cB.w};
            float wv[8] = {wA.x, wA.y, wA.z, wA.w, wB.x, wB.y, wB.z, wB.w};
            short8 p0v = *(const short8*)&Ps[wib * 2][idx];
            short8 p1v = *(const short8*)&Ps[wib * 2 + 1][idx];
            short8 vv = *(const short8*)(Vr + idx);
            #pragma unroll
            for (int e = 0; e < 8; ++e) {
                pd0 += b2f((unsigned short)p0v[e]) * wv[e];
                pd1 += b2f((unsigned short)p1v[e]) * wv[e];
                xo  += b2f((unsigned short)vv[e]) * cv[e];
            }
        }
        #pragma unroll
        for (int o = 1; o < 64; o <<= 1) {
            pd0 += __shfl_xor(pd0, o, 64); pd1 += __shfl_xor(pd1, o, 64);
            xo += __shfl_xor(xo, o, 64);
        }
        wdiv += (1.f / 12.f) * (u0 * pd0 + u1 * pd1);
        if (lane == 0) {
            out[jx] = x0[jx] + xo + b3[jx];
            wred[wib] = wdiv;
        }
    }
    __syncthreads();
    if (t == 0) {
        float dsum = wred[0] + wred[1] + wred[2] + wred[3];
        atomicAdd((float*)(sync + 4096 + (b & 15) * 16), dsum);
        asm volatile("s_waitcnt vmcnt(0)" ::: "memory");
        atomicAdd(sync + 4352, 1u);
    }
    if (b == 0 && wib == 0) {
        if (lane == 0) {
            while (__hip_atomic_load(sync + 4352, __ATOMIC_RELAXED, __HIP_MEMORY_SCOPE_AGENT) < NCB)
                __builtin_amdgcn_s_sleep(2);
        }
        float v = 0.f;
        if (lane < 16) {
            unsigned du = __hip_atomic_load(sync + 4096 + lane * 16,
                                            __ATOMIC_RELAXED, __HIP_MEMORY_SCOPE_AGENT);
            v = __uint_as_float(du);
        }
        #pragma unroll
        for (int o = 1; o < 64; o <<= 1) v += __shfl_xor(v, o, 64);
        if (lane == 0) out[DD] = logq_r - v;
    }
}

extern "C" void kernel_launch(void* const* d_in, const int* in_sizes, int n_in,
                              void* d_out, int out_size, void* d_ws, size_t ws_size,
                              hipStream_t stream) {
    const float* x0 = (const float*)d_in[0];
    const float* W1 = (const float*)d_in[1];
    const float* b1 = (const float*)d_in[2];
    const float* wt = (const float*)d_in[3];
    const float* W2 = (const float*)d_in[4];
    const float* b2 = (const float*)d_in[5];
    const float* W3 = (const float*)d_in[6];
    const float* b3 = (const float*)d_in[7];
    float* out = (float*)d_out;

    char* ws = (char*)d_ws;
    const size_t MB = 1024 * 1024;
    unsigned short* Pb  = (unsigned short*)(ws);            // 8 MB
    unsigned short* W2T = (unsigned short*)(ws + 8 * MB);   // 8 MB
    unsigned short* W3T = (unsigned short*)(ws + 16 * MB);  // 4 MB
    unsigned short* Mb  = (unsigned short*)(ws + 20 * MB);  // 8 MB
    unsigned short* W1T = (unsigned short*)(ws + 28 * MB);  // 4 MB
    unsigned short* W3b = (unsigned short*)(ws + 32 * MB);  // 4 MB
    float* fb = (float*)(ws + 36 * MB);
    float* c1      = fb;                       // 2048
    float* A1g     = fb + 2048;                // 2048
    float* h1_g    = fb + 4096;                // 2048
    float* h2_g    = fb + 6144;                // 2048
    float* hacc_g  = fb + 8192;                // 2048
    unsigned* sync = (unsigned*)(fb + 10240);  // 4368 uints

    k_tr<<<2048, 256, 0, stream>>>(W1, W2, W3, W1T, W2T, W3T, W3b, sync);
    k_gemmP<<<256, 256, 0, stream>>>(W1T, W3b, W2, b3, x0, Mb, Pb, c1, A1g);
    k_chain<<<NCB, 256, 0, stream>>>(Mb, Pb, W2T, W3T, x0, b1, wt, b2, b3, c1, A1g,
                                     h1_g, h2_g, hacc_g, out, sync);
}

// Round 17
// 155.473 us; speedup vs baseline: 1.1396x; 1.0584x over previous
//
#include <hip/hip_runtime.h>
#include <math.h>

#define DD 1024
#define HH 2048
#define NCB 256

typedef float f32x4 __attribute__((ext_vector_type(4)));
typedef short short8 __attribute__((ext_vector_type(8)));

__device__ __forceinline__ float b2f(unsigned short u) {
    return __uint_as_float(((unsigned int)u) << 16);
}
__device__ __forceinline__ unsigned short f2b(float f) {
    unsigned int x = __float_as_uint(f);
    unsigned int r = (x + 0x7FFFu + ((x >> 16) & 1u)) >> 16;
    return (unsigned short)r;
}
__device__ __forceinline__ float ald(const float* p) {
    return __hip_atomic_load(p, __ATOMIC_RELAXED, __HIP_MEMORY_SCOPE_AGENT);
}
__device__ __forceinline__ void ast(float* p, float v) {
    __hip_atomic_store(p, v, __ATOMIC_RELAXED, __HIP_MEMORY_SCOPE_AGENT);
}

// ---------------- transposes: [0,512) W1T | [512,1536) W2T | [1536,2048) W3T + W3b ----------------
__global__ __launch_bounds__(256) void k_tr(const float* __restrict__ W1,
                                            const float* __restrict__ W2,
                                            const float* __restrict__ W3,
                                            unsigned short* __restrict__ W1T,
                                            unsigned short* __restrict__ W2T,
                                            unsigned short* __restrict__ W3T,
                                            unsigned short* __restrict__ W3b,
                                            unsigned* __restrict__ sync) {
    __shared__ float tile[64][65];
    const int b = blockIdx.x, t = threadIdx.x;
    if (b == 0) {
        #pragma unroll
        for (int q = 0; q < 18; ++q) {
            int i = t + q * 256;
            if (i < 4368) sync[i] = 0u;
        }
    }
    const float* in; unsigned short* out; int R, C, bx, by;
    bool isW3 = false;
    if (b < 512)       { int bb = b;        in = W1; out = W1T; R = DD; C = HH; bx = bb & 31; by = bb >> 5; }
    else if (b < 1536) { int bb = b - 512;  in = W2; out = W2T; R = HH; C = HH; bx = bb & 31; by = bb >> 5; }
    else               { int bb = b - 1536; in = W3; out = W3T; R = HH; C = DD; bx = bb & 15; by = bb >> 4; isW3 = true; }
    const int c0 = bx * 64, r0 = by * 64;
    const int cc = t & 63, rb = t >> 6;
    #pragma unroll
    for (int p = 0; p < 16; ++p) {
        int rr = p * 4 + rb;
        float v = in[(size_t)(r0 + rr) * C + c0 + cc];
        tile[rr][cc] = v;
        if (isW3) W3b[(size_t)(r0 + rr) * DD + c0 + cc] = f2b(v);
    }
    __syncthreads();
    #pragma unroll
    for (int p = 0; p < 16; ++p) {
        int rr = p * 4 + rb;
        out[(size_t)(c0 + rr) * R + r0 + cc] = f2b(tile[cc][rr]);
    }
}

// ---------------- M = W1^T W3^T, P = M .* W2, c1, A1  — 64x128 tiles, 512 blocks (2/CU) ----------------
__global__ __launch_bounds__(256) void k_gemmP(const unsigned short* __restrict__ W1T,
                                               const unsigned short* __restrict__ W3b,
                                               const float* __restrict__ W2,
                                               const float* __restrict__ b3,
                                               const float* __restrict__ x0,
                                               unsigned short* __restrict__ Mb,
                                               unsigned short* __restrict__ Pb,
                                               float* __restrict__ c1,
                                               float* __restrict__ A1g) {
    __shared__ unsigned short At[64][40];    // 64 m-rows x 32 K
    __shared__ unsigned short Bt[128][40];   // 128 k-cols x 32 K
    const int b = blockIdx.x, t = threadIdx.x;
    const int m0 = (b & 31) * 64;    // same-m0 blocks: b stride 32 -> same XCD (32%8==0)
    const int k0 = (b >> 5) * 128;
    const int wv = t >> 6, l = t & 63;
    const int fr = l & 15, fg = l >> 4;
    const int ra = t & 63, ha = t >> 6;      // At staging: row, 16B-chunk
    const int rb2 = t & 127, hb = t >> 7;    // Bt staging: row, 32B-chunk
    const bool do_aux = ((b >> 5) == 0) && (t < 64);
    float c1acc = 0.f, a1acc = 0.f;

    f32x4 acc[4][2] = {};
    for (int i0 = 0; i0 < DD; i0 += 32) {
        {
            const float4* sa = (const float4*)(W1T + (size_t)(m0 + ra) * DD + i0 + ha * 8);
            float4 a0 = sa[0];
            const float4* sb = (const float4*)(W3b + (size_t)(k0 + rb2) * DD + i0 + hb * 16);
            float4 b0 = sb[0], b1 = sb[1];
            *(float4*)&At[ra][ha * 8] = a0;
            float4* db = (float4*)&Bt[rb2][hb * 16];
            db[0] = b0; db[1] = b1;
        }
        __syncthreads();
        if (do_aux) {
            #pragma unroll
            for (int i = 0; i < 32; ++i) {
                float w1v = b2f(At[t][i]);
                c1acc += w1v * b3[i0 + i];
                a1acc += w1v * x0[i0 + i];
            }
        }
        short8 af[4], bf[2];
        #pragma unroll
        for (int a = 0; a < 4; ++a)
            af[a] = *(const short8*)&At[a * 16 + fr][fg * 8];
        #pragma unroll
        for (int bq = 0; bq < 2; ++bq)
            bf[bq] = *(const short8*)&Bt[wv * 32 + bq * 16 + fr][fg * 8];
        #pragma unroll
        for (int a = 0; a < 4; ++a)
            #pragma unroll
            for (int bq = 0; bq < 2; ++bq)
                acc[a][bq] = __builtin_amdgcn_mfma_f32_16x16x32_bf16(af[a], bf[bq], acc[a][bq], 0, 0, 0);
        __syncthreads();
    }
    if (do_aux) { c1[m0 + t] = c1acc; A1g[m0 + t] = a1acc; }
    #pragma unroll
    for (int a = 0; a < 4; ++a) {
        #pragma unroll
        for (int bq = 0; bq < 2; ++bq) {
            #pragma unroll
            for (int j = 0; j < 4; ++j) {
                int row = m0 + a * 16 + fg * 4 + j;
                int col = k0 + wv * 32 + bq * 16 + fr;
                size_t idx = (size_t)row * HH + col;
                float m = acc[a][bq][j];
                Mb[idx] = f2b(m);
                Pb[idx] = f2b(m * W2[idx]);
            }
        }
    }
}

// ---------------- grid barrier: arrive / wait split (agent scope, direct scan) ----------------
__device__ __forceinline__ void garrive(unsigned* sync, int b, unsigned g) {
    __syncthreads();
    if (threadIdx.x == 0) {
        asm volatile("s_waitcnt vmcnt(0)" ::: "memory");
        __hip_atomic_store(&sync[b << 4], g, __ATOMIC_RELAXED, __HIP_MEMORY_SCOPE_AGENT);
    }
}
__device__ __forceinline__ void gwait(unsigned* sync, unsigned g) {
    if (threadIdx.x < 64) {
        while (true) {
            bool ok = true;
            #pragma unroll
            for (int k = 0; k < 4; ++k) {
                unsigned f = __hip_atomic_load(&sync[(threadIdx.x + (k << 6)) << 4],
                                               __ATOMIC_RELAXED, __HIP_MEMORY_SCOPE_AGENT);
                ok &= (f >= g);
            }
            if (!__any((int)(!ok))) break;
            __builtin_amdgcn_s_sleep(1);
        }
    }
    __syncthreads();
}
__device__ __forceinline__ void gbar(unsigned* sync, int b, unsigned g) {
    garrive(sync, b, g);
    gwait(sync, g);
}

// ---------------- persistent RK4 chain: preload hidden under first sync waits ----------------
__global__ __launch_bounds__(256, 1) void k_chain(
    const unsigned short* __restrict__ Mb,
    const unsigned short* __restrict__ Pb,
    const unsigned short* __restrict__ W2T,
    const unsigned short* __restrict__ W3T,
    const float* __restrict__ x0,
    const float* __restrict__ b1, const float* __restrict__ wt,
    const float* __restrict__ b2, const float* __restrict__ b3,
    const float* __restrict__ c1, const float* __restrict__ A1g,
    float* __restrict__ h1_g, float* __restrict__ h2_g, float* __restrict__ hacc_g,
    float* __restrict__ out,
    unsigned* __restrict__ sync) {
    __shared__ unsigned short Ms[8][2048];
    __shared__ unsigned short Ps[8][2048];
    __shared__ unsigned short Qs[8][2048];
    __shared__ float vecH[2048];
    __shared__ float vecW[2048];
    __shared__ float wred[4];
    const int t = threadIdx.x, b = blockIdx.x;
    const int wib = t >> 6, lane = t & 63;
    const int gw2 = (b << 3) + (wib << 1);
    const int jx = (b << 2) + wib;
    unsigned g = 0;

    const unsigned short* mp = Mb + (size_t)gw2 * HH;
    const unsigned short* pp = Pb + (size_t)gw2 * HH;
    const unsigned short* qp = W2T + (size_t)gw2 * HH;

    const float bb1_0 = b1[gw2], bb1_1 = b1[gw2 + 1];
    const float wt_0 = wt[gw2], wt_1 = wt[gw2 + 1];
    const float bb2_0 = b2[gw2], bb2_1 = b2[gw2 + 1];
    const float c1_0 = c1[gw2], c1_1 = c1[gw2 + 1];

    float A1_0 = 0.f, A1_1 = 0.f;
    float u0 = 0.f, u1 = 0.f;
    float hc0 = 0.f, hc1 = 0.f;
    float wdiv = 0.f;

    float logq_r = 0.f;
    if (b == 0 && wib == 0) {
        float ssum = 0.f;
        #pragma unroll
        for (int q = 0; q < 16; ++q) { float xv = x0[lane + (q << 6)]; ssum += xv * xv; }
        #pragma unroll
        for (int o = 1; o < 64; o <<= 1) ssum += __shfl_xor(ssum, o, 64);
        logq_r = -0.5f * ssum - 0.5f * 1024.0f * 1.8378770664093453f;
    }

    // ======== stage 0, Phase A (needs only A1g) — arrive ASAP ========
    {
        A1_0 = A1g[gw2]; A1_1 = A1g[gw2 + 1];
        float h0 = tanhf(A1_0 + bb1_0);          // tcur = 0
        float h1v = tanhf(A1_1 + bb1_1);
        u0 = 1.f - h0 * h0; u1 = 1.f - h1v * h1v;
        if (lane == 0) { ast(h1_g + gw2, h0); ast(h1_g + gw2 + 1, h1v); }
    }
    garrive(sync, b, ++g);
    // preload Qs (wave-private rows) — hidden under round-1 wait
    #pragma unroll
    for (int rep = 0; rep < 4; ++rep) {
        const int idx = rep * 512 + lane * 8;
        *(short8*)&Qs[wib * 2][idx]     = *(const short8*)(qp + idx);
        *(short8*)&Qs[wib * 2 + 1][idx] = *(const short8*)(qp + HH + idx);
    }
    gwait(sync, g);

    // ======== stage 0, Phase B ========
    #pragma unroll
    for (int q = 0; q < 8; ++q) {
        int i = t + (q << 8);
        vecH[i] = ald(h1_g + i);
    }
    __syncthreads();
    {
        float a0 = 0.f, a1 = 0.f;
        #pragma unroll
        for (int rep = 0; rep < 4; ++rep) {
            const int idx = rep * 512 + lane * 8;
            float4 hA = *(const float4*)(vecH + idx);
            float4 hB = *(const float4*)(vecH + idx + 4);
            float hv[8] = {hA.x, hA.y, hA.z, hA.w, hB.x, hB.y, hB.z, hB.w};
            short8 r0 = *(const short8*)&Qs[wib * 2][idx];
            short8 r1 = *(const short8*)&Qs[wib * 2 + 1][idx];
            #pragma unroll
            for (int e = 0; e < 8; ++e) {
                a0 += b2f((unsigned short)r0[e]) * hv[e];
                a1 += b2f((unsigned short)r1[e]) * hv[e];
            }
        }
        #pragma unroll
        for (int o = 1; o < 64; o <<= 1) {
            a0 += __shfl_xor(a0, o, 64); a1 += __shfl_xor(a1, o, 64);
        }
        float q0 = tanhf(a0 + bb2_0), q1 = tanhf(a1 + bb2_1);
        hc0 += (1.f / 12.f) * q0; hc1 += (1.f / 12.f) * q1;   // cs for ss==0
        if (lane == 0) {
            ast(h2_g + gw2, q0); ast(h2_g + gw2 + 1, q1);
        }
    }
    garrive(sync, b, ++g);
    // preload Ms, Ps — hidden under round-2 wait
    #pragma unroll
    for (int rep = 0; rep < 4; ++rep) {
        const int idx = rep * 512 + lane * 8;
        *(short8*)&Ms[wib * 2][idx]     = *(const short8*)(mp + idx);
        *(short8*)&Ms[wib * 2 + 1][idx] = *(const short8*)(mp + HH + idx);
        *(short8*)&Ps[wib * 2][idx]     = *(const short8*)(pp + idx);
        *(short8*)&Ps[wib * 2 + 1][idx] = *(const short8*)(pp + HH + idx);
    }
    gwait(sync, g);

    // ======== stages 1..7 ========
    for (int s = 1; s < 8; ++s) {
        const int ss = s & 3;
        const float tcur = (s >> 2) * 0.5f + ((ss == 0) ? 0.f : (ss == 3) ? 0.5f : 0.25f);

        // ---- Phase A ----
        {
            #pragma unroll
            for (int q = 0; q < 8; ++q) {
                int i = t + (q << 8);
                float h2v = ald(h2_g + i);
                float sv = (ss == 0) ? ald(hacc_g + i) : h2v;
                vecH[i] = sv;
                vecW[i] = 1.f - h2v * h2v;
            }
            __syncthreads();
            float md0 = 0.f, md1 = 0.f, pd0 = 0.f, pd1 = 0.f;
            #pragma unroll
            for (int rep = 0; rep < 4; ++rep) {
                const int idx = rep * 512 + lane * 8;
                float4 hA = *(const float4*)(vecH + idx);
                float4 hB = *(const float4*)(vecH + idx + 4);
                float4 wA = *(const float4*)(vecW + idx);
                float4 wB = *(const float4*)(vecW + idx + 4);
                float hv[8] = {hA.x, hA.y, hA.z, hA.w, hB.x, hB.y, hB.z, hB.w};
                float wv[8] = {wA.x, wA.y, wA.z, wA.w, wB.x, wB.y, wB.z, wB.w};
                short8 m0v = *(const short8*)&Ms[wib * 2][idx];
                short8 m1v = *(const short8*)&Ms[wib * 2 + 1][idx];
                short8 p0v = *(const short8*)&Ps[wib * 2][idx];
                short8 p1v = *(const short8*)&Ps[wib * 2 + 1][idx];
                #pragma unroll
                for (int e = 0; e < 8; ++e) {
                    md0 += b2f((unsigned short)m0v[e]) * hv[e];
                    md1 += b2f((unsigned short)m1v[e]) * hv[e];
                    pd0 += b2f((unsigned short)p0v[e]) * wv[e];
                    pd1 += b2f((unsigned short)p1v[e]) * wv[e];
                }
            }
            #pragma unroll
            for (int o = 1; o < 64; o <<= 1) {
                md0 += __shfl_xor(md0, o, 64); md1 += __shfl_xor(md1, o, 64);
                pd0 += __shfl_xor(pd0, o, 64); pd1 += __shfl_xor(pd1, o, 64);
            }
            const int sp = (s - 1) & 3;
            const float cprev = (sp == 1 || sp == 2) ? (1.f / 6.f) : (1.f / 12.f);
            wdiv += cprev * (u0 * pd0 + u1 * pd1);
            float pre0, pre1;
            if (ss == 0) {
                A1_0 += md0 + 0.5f * c1_0; A1_1 += md1 + 0.5f * c1_1;
                pre0 = A1_0 + bb1_0 + tcur * wt_0; pre1 = A1_1 + bb1_1 + tcur * wt_1;
            } else {
                const float a = (ss == 3) ? 0.5f : 0.25f;
                pre0 = A1_0 + a * (md0 + c1_0) + bb1_0 + tcur * wt_0;
                pre1 = A1_1 + a * (md1 + c1_1) + bb1_1 + tcur * wt_1;
            }
            float h0 = tanhf(pre0), h1v = tanhf(pre1);
            u0 = 1.f - h0 * h0; u1 = 1.f - h1v * h1v;
            if (lane == 0) { ast(h1_g + gw2, h0); ast(h1_g + gw2 + 1, h1v); }
        }
        gbar(sync, b, ++g);

        // ---- Phase B ----
        #pragma unroll
        for (int q = 0; q < 8; ++q) {
            int i = t + (q << 8);
            vecH[i] = ald(h1_g + i);
        }
        __syncthreads();
        {
            float a0 = 0.f, a1 = 0.f;
            #pragma unroll
            for (int rep = 0; rep < 4; ++rep) {
                const int idx = rep * 512 + lane * 8;
                float4 hA = *(const float4*)(vecH + idx);
                float4 hB = *(const float4*)(vecH + idx + 4);
                float hv[8] = {hA.x, hA.y, hA.z, hA.w, hB.x, hB.y, hB.z, hB.w};
                short8 r0 = *(const short8*)&Qs[wib * 2][idx];
                short8 r1 = *(const short8*)&Qs[wib * 2 + 1][idx];
                #pragma unroll
                for (int e = 0; e < 8; ++e) {
                    a0 += b2f((unsigned short)r0[e]) * hv[e];
                    a1 += b2f((unsigned short)r1[e]) * hv[e];
                }
            }
            #pragma unroll
            for (int o = 1; o < 64; o <<= 1) {
                a0 += __shfl_xor(a0, o, 64); a1 += __shfl_xor(a1, o, 64);
            }
            float q0 = tanhf(a0 + bb2_0), q1 = tanhf(a1 + bb2_1);
            const float cs = (ss == 1 || ss == 2) ? (1.f / 6.f) : (1.f / 12.f);
            hc0 += cs * q0; hc1 += cs * q1;
            if (lane == 0) {
                ast(h2_g + gw2, q0); ast(h2_g + gw2 + 1, q1);
                if (ss == 3) { ast(hacc_g + gw2, hc0); ast(hacc_g + gw2 + 1, hc1); }
            }
        }
        gbar(sync, b, ++g);
    }

    // ================= Epilogue =================
    {
        #pragma unroll
        for (int q = 0; q < 8; ++q) {
            int i = t + (q << 8);
            float h2v = ald(h2_g + i);
            vecH[i] = ald(hacc_g + i);
            vecW[i] = 1.f - h2v * h2v;
        }
        __syncthreads();
        float pd0 = 0.f, pd1 = 0.f, xo = 0.f;
        const unsigned short* Vr = W3T + (size_t)jx * HH;
        #pragma unroll
        for (int rep = 0; rep < 4; ++rep) {
            const int idx = rep * 512 + lane * 8;
            float4 cA = *(const float4*)(vecH + idx);
            float4 cB = *(const float4*)(vecH + idx + 4);
            float4 wA = *(const float4*)(vecW + idx);
            float4 wB = *(const float4*)(vecW + idx + 4);
            float cv[8] = {cA.x, cA.y, cA.z, cA.w, cB.x, cB.y, cB.z, cB.w};
            float wv[8] = {wA.x, wA.y, wA.z, wA.w, wB.x, wB.y, wB.z, wB.w};
            short8 p0v = *(const short8*)&Ps[wib * 2][idx];
            short8 p1v = *(const short8*)&Ps[wib * 2 + 1][idx];
            short8 vv = *(const short8*)(Vr + idx);
            #pragma unroll
            for (int e = 0; e < 8; ++e) {
                pd0 += b2f((unsigned short)p0v[e]) * wv[e];
                pd1 += b2f((unsigned short)p1v[e]) * wv[e];
                xo  += b2f((unsigned short)vv[e]) * cv[e];
            }
        }
        #pragma unroll
        for (int o = 1; o < 64; o <<= 1) {
            pd0 += __shfl_xor(pd0, o, 64); pd1 += __shfl_xor(pd1, o, 64);
            xo += __shfl_xor(xo, o, 64);
        }
        wdiv += (1.f / 12.f) * (u0 * pd0 + u1 * pd1);
        if (lane == 0) {
            out[jx] = x0[jx] + xo + b3[jx];
            wred[wib] = wdiv;
        }
    }
    __syncthreads();
    if (t == 0) {
        float dsum = wred[0] + wred[1] + wred[2] + wred[3];
        atomicAdd((float*)(sync + 4096 + (b & 15) * 16), dsum);
        asm volatile("s_waitcnt vmcnt(0)" ::: "memory");
        atomicAdd(sync + 4352, 1u);
    }
    if (b == 0 && wib == 0) {
        if (lane == 0) {
            while (__hip_atomic_load(sync + 4352, __ATOMIC_RELAXED, __HIP_MEMORY_SCOPE_AGENT) < NCB)
                __builtin_amdgcn_s_sleep(2);
        }
        float v = 0.f;
        if (lane < 16) {
            unsigned du = __hip_atomic_load(sync + 4096 + lane * 16,
                                            __ATOMIC_RELAXED, __HIP_MEMORY_SCOPE_AGENT);
            v = __uint_as_float(du);
        }
        #pragma unroll
        for (int o = 1; o < 64; o <<= 1) v += __shfl_xor(v, o, 64);
        if (lane == 0) out[DD] = logq_r - v;
    }
}

extern "C" void kernel_launch(void* const* d_in, const int* in_sizes, int n_in,
                              void* d_out, int out_size, void* d_ws, size_t ws_size,
                              hipStream_t stream) {
    const float* x0 = (const float*)d_in[0];
    const float* W1 = (const float*)d_in[1];
    const float* b1 = (const float*)d_in[2];
    const float* wt = (const float*)d_in[3];
    const float* W2 = (const float*)d_in[4];
    const float* b2 = (const float*)d_in[5];
    const float* W3 = (const float*)d_in[6];
    const float* b3 = (const float*)d_in[7];
    float* out = (float*)d_out;

    char* ws = (char*)d_ws;
    const size_t MB = 1024 * 1024;
    unsigned short* Pb  = (unsigned short*)(ws);            // 8 MB
    unsigned short* W2T = (unsigned short*)(ws + 8 * MB);   // 8 MB
    unsigned short* W3T = (unsigned short*)(ws + 16 * MB);  // 4 MB
    unsigned short* Mb  = (unsigned short*)(ws + 20 * MB);  // 8 MB
    unsigned short* W1T = (unsigned short*)(ws + 28 * MB);  // 4 MB
    unsigned short* W3b = (unsigned short*)(ws + 32 * MB);  // 4 MB
    float* fb = (float*)(ws + 36 * MB);
    float* c1      = fb;                       // 2048
    float* A1g     = fb + 2048;                // 2048
    float* h1_g    = fb + 4096;                // 2048
    float* h2_g    = fb + 6144;                // 2048
    float* hacc_g  = fb + 8192;                // 2048
    unsigned* sync = (unsigned*)(fb + 10240);  // 4368 uints

    k_tr<<<2048, 256, 0, stream>>>(W1, W2, W3, W1T, W2T, W3T, W3b, sync);
    k_gemmP<<<512, 256, 0, stream>>>(W1T, W3b, W2, b3, x0, Mb, Pb, c1, A1g);
    k_chain<<<NCB, 256, 0, stream>>>(Mb, Pb, W2T, W3T, x0, b1, wt, b2, b3, c1, A1g,
                                     h1_g, h2_g, hacc_g, out, sync);
}

// Round 18
// 153.597 us; speedup vs baseline: 1.1535x; 1.0122x over previous
//
#include <hip/hip_runtime.h>
#include <math.h>

#define DD 1024
#define HH 2048
#define NCB 256

typedef float f32x4 __attribute__((ext_vector_type(4)));
typedef short short8 __attribute__((ext_vector_type(8)));

__device__ __forceinline__ float b2f(unsigned short u) {
    return __uint_as_float(((unsigned int)u) << 16);
}
__device__ __forceinline__ unsigned short f2b(float f) {
    unsigned int x = __float_as_uint(f);
    unsigned int r = (x + 0x7FFFu + ((x >> 16) & 1u)) >> 16;
    return (unsigned short)r;
}
__device__ __forceinline__ float ald(const float* p) {
    return __hip_atomic_load(p, __ATOMIC_RELAXED, __HIP_MEMORY_SCOPE_AGENT);
}
__device__ __forceinline__ void ast(float* p, float v) {
    __hip_atomic_store(p, v, __ATOMIC_RELAXED, __HIP_MEMORY_SCOPE_AGENT);
}

// ---------------- transposes: [0,512) W1T | [512,1536) W2T | [1536,2048) W3T + W3b ----------------
__global__ __launch_bounds__(256) void k_tr(const float* __restrict__ W1,
                                            const float* __restrict__ W2,
                                            const float* __restrict__ W3,
                                            unsigned short* __restrict__ W1T,
                                            unsigned short* __restrict__ W2T,
                                            unsigned short* __restrict__ W3T,
                                            unsigned short* __restrict__ W3b,
                                            unsigned* __restrict__ sync) {
    __shared__ float tile[64][65];
    const int b = blockIdx.x, t = threadIdx.x;
    if (b == 0) {
        #pragma unroll
        for (int q = 0; q < 18; ++q) {
            int i = t + q * 256;
            if (i < 4368) sync[i] = 0u;
        }
    }
    const float* in; unsigned short* out; int R, C, bx, by;
    bool isW3 = false;
    if (b < 512)       { int bb = b;        in = W1; out = W1T; R = DD; C = HH; bx = bb & 31; by = bb >> 5; }
    else if (b < 1536) { int bb = b - 512;  in = W2; out = W2T; R = HH; C = HH; bx = bb & 31; by = bb >> 5; }
    else               { int bb = b - 1536; in = W3; out = W3T; R = HH; C = DD; bx = bb & 15; by = bb >> 4; isW3 = true; }
    const int c0 = bx * 64, r0 = by * 64;
    const int cc = t & 63, rb = t >> 6;
    #pragma unroll
    for (int p = 0; p < 16; ++p) {
        int rr = p * 4 + rb;
        float v = in[(size_t)(r0 + rr) * C + c0 + cc];
        tile[rr][cc] = v;
        if (isW3) W3b[(size_t)(r0 + rr) * DD + c0 + cc] = f2b(v);
    }
    __syncthreads();
    #pragma unroll
    for (int p = 0; p < 16; ++p) {
        int rr = p * 4 + rb;
        out[(size_t)(c0 + rr) * R + r0 + cc] = f2b(tile[cc][rr]);
    }
}

// ---------------- M = W1^T W3^T, P = M .* W2, c1, A1 — 64x128 tiles, K-step 64, 512 blocks ----------------
__global__ __launch_bounds__(256) void k_gemmP(const unsigned short* __restrict__ W1T,
                                               const unsigned short* __restrict__ W3b,
                                               const float* __restrict__ W2,
                                               const float* __restrict__ b3,
                                               const float* __restrict__ x0,
                                               unsigned short* __restrict__ Mb,
                                               unsigned short* __restrict__ Pb,
                                               float* __restrict__ c1,
                                               float* __restrict__ A1g) {
    __shared__ unsigned short At[64][72];    // 64 m-rows x 64 K (pad to 72)
    __shared__ unsigned short Bt[128][72];   // 128 k-cols x 64 K
    const int b = blockIdx.x, t = threadIdx.x;
    const int m0 = (b & 31) * 64;    // same-m0 blocks: stride 32 -> same XCD
    const int k0 = (b >> 5) * 128;
    const int wv = t >> 6, l = t & 63;
    const int fr = l & 15, fg = l >> 4;
    const int ra = t & 63, ha = t >> 6;      // At staging: row, 32B chunk (16 shorts)
    const int rb2 = t & 127, hb = t >> 7;    // Bt staging: row, 64B chunk (32 shorts)
    const bool do_aux = ((b >> 5) == 0) && (t < 64);
    float c1acc = 0.f, a1acc = 0.f;

    f32x4 acc[4][2] = {};
    for (int i0 = 0; i0 < DD; i0 += 64) {
        {
            const float4* sa = (const float4*)(W1T + (size_t)(m0 + ra) * DD + i0 + ha * 16);
            float4 a0 = sa[0], a1 = sa[1];
            const float4* sb = (const float4*)(W3b + (size_t)(k0 + rb2) * DD + i0 + hb * 32);
            float4 b0 = sb[0], b1 = sb[1], b2v = sb[2], b3v = sb[3];
            float4* da = (float4*)&At[ra][ha * 16];
            da[0] = a0; da[1] = a1;
            float4* db = (float4*)&Bt[rb2][hb * 32];
            db[0] = b0; db[1] = b1; db[2] = b2v; db[3] = b3v;
        }
        __syncthreads();
        if (do_aux) {
            #pragma unroll
            for (int i = 0; i < 64; ++i) {
                float w1v = b2f(At[t][i]);
                c1acc += w1v * b3[i0 + i];
                a1acc += w1v * x0[i0 + i];
            }
        }
        #pragma unroll
        for (int kk = 0; kk < 2; ++kk) {
            short8 af[4], bf[2];
            #pragma unroll
            for (int a = 0; a < 4; ++a)
                af[a] = *(const short8*)&At[a * 16 + fr][kk * 32 + fg * 8];
            #pragma unroll
            for (int bq = 0; bq < 2; ++bq)
                bf[bq] = *(const short8*)&Bt[wv * 32 + bq * 16 + fr][kk * 32 + fg * 8];
            #pragma unroll
            for (int a = 0; a < 4; ++a)
                #pragma unroll
                for (int bq = 0; bq < 2; ++bq)
                    acc[a][bq] = __builtin_amdgcn_mfma_f32_16x16x32_bf16(af[a], bf[bq], acc[a][bq], 0, 0, 0);
        }
        __syncthreads();
    }
    if (do_aux) { c1[m0 + t] = c1acc; A1g[m0 + t] = a1acc; }
    #pragma unroll
    for (int a = 0; a < 4; ++a) {
        #pragma unroll
        for (int bq = 0; bq < 2; ++bq) {
            #pragma unroll
            for (int j = 0; j < 4; ++j) {
                int row = m0 + a * 16 + fg * 4 + j;
                int col = k0 + wv * 32 + bq * 16 + fr;
                size_t idx = (size_t)row * HH + col;
                float m = acc[a][bq][j];
                Mb[idx] = f2b(m);
                Pb[idx] = f2b(m * W2[idx]);
            }
        }
    }
}

// ---------------- grid barrier: arrive / wait split (agent scope, direct scan) ----------------
__device__ __forceinline__ void garrive(unsigned* sync, int b, unsigned g) {
    __syncthreads();
    if (threadIdx.x == 0) {
        asm volatile("s_waitcnt vmcnt(0)" ::: "memory");
        __hip_atomic_store(&sync[b << 4], g, __ATOMIC_RELAXED, __HIP_MEMORY_SCOPE_AGENT);
    }
}
__device__ __forceinline__ void gwait(unsigned* sync, unsigned g) {
    if (threadIdx.x < 64) {
        while (true) {
            bool ok = true;
            #pragma unroll
            for (int k = 0; k < 4; ++k) {
                unsigned f = __hip_atomic_load(&sync[(threadIdx.x + (k << 6)) << 4],
                                               __ATOMIC_RELAXED, __HIP_MEMORY_SCOPE_AGENT);
                ok &= (f >= g);
            }
            if (!__any((int)(!ok))) break;
            __builtin_amdgcn_s_sleep(1);
        }
    }
    __syncthreads();
}
__device__ __forceinline__ void gbar(unsigned* sync, int b, unsigned g) {
    garrive(sync, b, g);
    gwait(sync, g);
}

// ---------------- persistent RK4 chain (identical to R17) ----------------
__global__ __launch_bounds__(256, 1) void k_chain(
    const unsigned short* __restrict__ Mb,
    const unsigned short* __restrict__ Pb,
    const unsigned short* __restrict__ W2T,
    const unsigned short* __restrict__ W3T,
    const float* __restrict__ x0,
    const float* __restrict__ b1, const float* __restrict__ wt,
    const float* __restrict__ b2, const float* __restrict__ b3,
    const float* __restrict__ c1, const float* __restrict__ A1g,
    float* __restrict__ h1_g, float* __restrict__ h2_g, float* __restrict__ hacc_g,
    float* __restrict__ out,
    unsigned* __restrict__ sync) {
    __shared__ unsigned short Ms[8][2048];
    __shared__ unsigned short Ps[8][2048];
    __shared__ unsigned short Qs[8][2048];
    __shared__ float vecH[2048];
    __shared__ float vecW[2048];
    __shared__ float wred[4];
    const int t = threadIdx.x, b = blockIdx.x;
    const int wib = t >> 6, lane = t & 63;
    const int gw2 = (b << 3) + (wib << 1);
    const int jx = (b << 2) + wib;
    unsigned g = 0;

    const unsigned short* mp = Mb + (size_t)gw2 * HH;
    const unsigned short* pp = Pb + (size_t)gw2 * HH;
    const unsigned short* qp = W2T + (size_t)gw2 * HH;

    const float bb1_0 = b1[gw2], bb1_1 = b1[gw2 + 1];
    const float wt_0 = wt[gw2], wt_1 = wt[gw2 + 1];
    const float bb2_0 = b2[gw2], bb2_1 = b2[gw2 + 1];
    const float c1_0 = c1[gw2], c1_1 = c1[gw2 + 1];

    float A1_0 = 0.f, A1_1 = 0.f;
    float u0 = 0.f, u1 = 0.f;
    float hc0 = 0.f, hc1 = 0.f;
    float wdiv = 0.f;

    float logq_r = 0.f;
    if (b == 0 && wib == 0) {
        float ssum = 0.f;
        #pragma unroll
        for (int q = 0; q < 16; ++q) { float xv = x0[lane + (q << 6)]; ssum += xv * xv; }
        #pragma unroll
        for (int o = 1; o < 64; o <<= 1) ssum += __shfl_xor(ssum, o, 64);
        logq_r = -0.5f * ssum - 0.5f * 1024.0f * 1.8378770664093453f;
    }

    // ======== stage 0, Phase A (needs only A1g) — arrive ASAP ========
    {
        A1_0 = A1g[gw2]; A1_1 = A1g[gw2 + 1];
        float h0 = tanhf(A1_0 + bb1_0);          // tcur = 0
        float h1v = tanhf(A1_1 + bb1_1);
        u0 = 1.f - h0 * h0; u1 = 1.f - h1v * h1v;
        if (lane == 0) { ast(h1_g + gw2, h0); ast(h1_g + gw2 + 1, h1v); }
    }
    garrive(sync, b, ++g);
    // preload Qs — hidden under round-1 wait
    #pragma unroll
    for (int rep = 0; rep < 4; ++rep) {
        const int idx = rep * 512 + lane * 8;
        *(short8*)&Qs[wib * 2][idx]     = *(const short8*)(qp + idx);
        *(short8*)&Qs[wib * 2 + 1][idx] = *(const short8*)(qp + HH + idx);
    }
    gwait(sync, g);

    // ======== stage 0, Phase B ========
    #pragma unroll
    for (int q = 0; q < 8; ++q) {
        int i = t + (q << 8);
        vecH[i] = ald(h1_g + i);
    }
    __syncthreads();
    {
        float a0 = 0.f, a1 = 0.f;
        #pragma unroll
        for (int rep = 0; rep < 4; ++rep) {
            const int idx = rep * 512 + lane * 8;
            float4 hA = *(const float4*)(vecH + idx);
            float4 hB = *(const float4*)(vecH + idx + 4);
            float hv[8] = {hA.x, hA.y, hA.z, hA.w, hB.x, hB.y, hB.z, hB.w};
            short8 r0 = *(const short8*)&Qs[wib * 2][idx];
            short8 r1 = *(const short8*)&Qs[wib * 2 + 1][idx];
            #pragma unroll
            for (int e = 0; e < 8; ++e) {
                a0 += b2f((unsigned short)r0[e]) * hv[e];
                a1 += b2f((unsigned short)r1[e]) * hv[e];
            }
        }
        #pragma unroll
        for (int o = 1; o < 64; o <<= 1) {
            a0 += __shfl_xor(a0, o, 64); a1 += __shfl_xor(a1, o, 64);
        }
        float q0 = tanhf(a0 + bb2_0), q1 = tanhf(a1 + bb2_1);
        hc0 += (1.f / 12.f) * q0; hc1 += (1.f / 12.f) * q1;
        if (lane == 0) {
            ast(h2_g + gw2, q0); ast(h2_g + gw2 + 1, q1);
        }
    }
    garrive(sync, b, ++g);
    // preload Ms, Ps — hidden under round-2 wait
    #pragma unroll
    for (int rep = 0; rep < 4; ++rep) {
        const int idx = rep * 512 + lane * 8;
        *(short8*)&Ms[wib * 2][idx]     = *(const short8*)(mp + idx);
        *(short8*)&Ms[wib * 2 + 1][idx] = *(const short8*)(mp + HH + idx);
        *(short8*)&Ps[wib * 2][idx]     = *(const short8*)(pp + idx);
        *(short8*)&Ps[wib * 2 + 1][idx] = *(const short8*)(pp + HH + idx);
    }
    gwait(sync, g);

    // ======== stages 1..7 ========
    for (int s = 1; s < 8; ++s) {
        const int ss = s & 3;
        const float tcur = (s >> 2) * 0.5f + ((ss == 0) ? 0.f : (ss == 3) ? 0.5f : 0.25f);

        // ---- Phase A ----
        {
            #pragma unroll
            for (int q = 0; q < 8; ++q) {
                int i = t + (q << 8);
                float h2v = ald(h2_g + i);
                float sv = (ss == 0) ? ald(hacc_g + i) : h2v;
                vecH[i] = sv;
                vecW[i] = 1.f - h2v * h2v;
            }
            __syncthreads();
            float md0 = 0.f, md1 = 0.f, pd0 = 0.f, pd1 = 0.f;
            #pragma unroll
            for (int rep = 0; rep < 4; ++rep) {
                const int idx = rep * 512 + lane * 8;
                float4 hA = *(const float4*)(vecH + idx);
                float4 hB = *(const float4*)(vecH + idx + 4);
                float4 wA = *(const float4*)(vecW + idx);
                float4 wB = *(const float4*)(vecW + idx + 4);
                float hv[8] = {hA.x, hA.y, hA.z, hA.w, hB.x, hB.y, hB.z, hB.w};
                float wv[8] = {wA.x, wA.y, wA.z, wA.w, wB.x, wB.y, wB.z, wB.w};
                short8 m0v = *(const short8*)&Ms[wib * 2][idx];
                short8 m1v = *(const short8*)&Ms[wib * 2 + 1][idx];
                short8 p0v = *(const short8*)&Ps[wib * 2][idx];
                short8 p1v = *(const short8*)&Ps[wib * 2 + 1][idx];
                #pragma unroll
                for (int e = 0; e < 8; ++e) {
                    md0 += b2f((unsigned short)m0v[e]) * hv[e];
                    md1 += b2f((unsigned short)m1v[e]) * hv[e];
                    pd0 += b2f((unsigned short)p0v[e]) * wv[e];
                    pd1 += b2f((unsigned short)p1v[e]) * wv[e];
                }
            }
            #pragma unroll
            for (int o = 1; o < 64; o <<= 1) {
                md0 += __shfl_xor(md0, o, 64); md1 += __shfl_xor(md1, o, 64);
                pd0 += __shfl_xor(pd0, o, 64); pd1 += __shfl_xor(pd1, o, 64);
            }
            const int sp = (s - 1) & 3;
            const float cprev = (sp == 1 || sp == 2) ? (1.f / 6.f) : (1.f / 12.f);
            wdiv += cprev * (u0 * pd0 + u1 * pd1);
            float pre0, pre1;
            if (ss == 0) {
                A1_0 += md0 + 0.5f * c1_0; A1_1 += md1 + 0.5f * c1_1;
                pre0 = A1_0 + bb1_0 + tcur * wt_0; pre1 = A1_1 + bb1_1 + tcur * wt_1;
            } else {
                const float a = (ss == 3) ? 0.5f : 0.25f;
                pre0 = A1_0 + a * (md0 + c1_0) + bb1_0 + tcur * wt_0;
                pre1 = A1_1 + a * (md1 + c1_1) + bb1_1 + tcur * wt_1;
            }
            float h0 = tanhf(pre0), h1v = tanhf(pre1);
            u0 = 1.f - h0 * h0; u1 = 1.f - h1v * h1v;
            if (lane == 0) { ast(h1_g + gw2, h0); ast(h1_g + gw2 + 1, h1v); }
        }
        gbar(sync, b, ++g);

        // ---- Phase B ----
        #pragma unroll
        for (int q = 0; q < 8; ++q) {
            int i = t + (q << 8);
            vecH[i] = ald(h1_g + i);
        }
        __syncthreads();
        {
            float a0 = 0.f, a1 = 0.f;
            #pragma unroll
            for (int rep = 0; rep < 4; ++rep) {
                const int idx = rep * 512 + lane * 8;
                float4 hA = *(const float4*)(vecH + idx);
                float4 hB = *(const float4*)(vecH + idx + 4);
                float hv[8] = {hA.x, hA.y, hA.z, hA.w, hB.x, hB.y, hB.z, hB.w};
                short8 r0 = *(const short8*)&Qs[wib * 2][idx];
                short8 r1 = *(const short8*)&Qs[wib * 2 + 1][idx];
                #pragma unroll
                for (int e = 0; e < 8; ++e) {
                    a0 += b2f((unsigned short)r0[e]) * hv[e];
                    a1 += b2f((unsigned short)r1[e]) * hv[e];
                }
            }
            #pragma unroll
            for (int o = 1; o < 64; o <<= 1) {
                a0 += __shfl_xor(a0, o, 64); a1 += __shfl_xor(a1, o, 64);
            }
            float q0 = tanhf(a0 + bb2_0), q1 = tanhf(a1 + bb2_1);
            const float cs = (ss == 1 || ss == 2) ? (1.f / 6.f) : (1.f / 12.f);
            hc0 += cs * q0; hc1 += cs * q1;
            if (lane == 0) {
                ast(h2_g + gw2, q0); ast(h2_g + gw2 + 1, q1);
                if (ss == 3) { ast(hacc_g + gw2, hc0); ast(hacc_g + gw2 + 1, hc1); }
            }
        }
        gbar(sync, b, ++g);
    }

    // ================= Epilogue =================
    {
        #pragma unroll
        for (int q = 0; q < 8; ++q) {
            int i = t + (q << 8);
            float h2v = ald(h2_g + i);
            vecH[i] = ald(hacc_g + i);
            vecW[i] = 1.f - h2v * h2v;
        }
        __syncthreads();
        float pd0 = 0.f, pd1 = 0.f, xo = 0.f;
        const unsigned short* Vr = W3T + (size_t)jx * HH;
        #pragma unroll
        for (int rep = 0; rep < 4; ++rep) {
            const int idx = rep * 512 + lane * 8;
            float4 cA = *(const float4*)(vecH + idx);
            float4 cB = *(const float4*)(vecH + idx + 4);
            float4 wA = *(const float4*)(vecW + idx);
            float4 wB = *(const float4*)(vecW + idx + 4);
            float cv[8] = {cA.x, cA.y, cA.z, cA.w, cB.x, cB.y, cB.z, cB.w};
            float wv[8] = {wA.x, wA.y, wA.z, wA.w, wB.x, wB.y, wB.z, wB.w};
            short8 p0v = *(const short8*)&Ps[wib * 2][idx];
            short8 p1v = *(const short8*)&Ps[wib * 2 + 1][idx];
            short8 vv = *(const short8*)(Vr + idx);
            #pragma unroll
            for (int e = 0; e < 8; ++e) {
                pd0 += b2f((unsigned short)p0v[e]) * wv[e];
                pd1 += b2f((unsigned short)p1v[e]) * wv[e];
                xo  += b2f((unsigned short)vv[e]) * cv[e];
            }
        }
        #pragma unroll
        for (int o = 1; o < 64; o <<= 1) {
            pd0 += __shfl_xor(pd0, o, 64); pd1 += __shfl_xor(pd1, o, 64);
            xo += __shfl_xor(xo, o, 64);
        }
        wdiv += (1.f / 12.f) * (u0 * pd0 + u1 * pd1);
        if (lane == 0) {
            out[jx] = x0[jx] + xo + b3[jx];
            wred[wib] = wdiv;
        }
    }
    __syncthreads();
    if (t == 0) {
        float dsum = wred[0] + wred[1] + wred[2] + wred[3];
        atomicAdd((float*)(sync + 4096 + (b & 15) * 16), dsum);
        asm volatile("s_waitcnt vmcnt(0)" ::: "memory");
        atomicAdd(sync + 4352, 1u);
    }
    if (b == 0 && wib == 0) {
        if (lane == 0) {
            while (__hip_atomic_load(sync + 4352, __ATOMIC_RELAXED, __HIP_MEMORY_SCOPE_AGENT) < NCB)
                __builtin_amdgcn_s_sleep(2);
        }
        float v = 0.f;
        if (lane < 16) {
            unsigned du = __hip_atomic_load(sync + 4096 + lane * 16,
                                            __ATOMIC_RELAXED, __HIP_MEMORY_SCOPE_AGENT);
            v = __uint_as_float(du);
        }
        #pragma unroll
        for (int o = 1; o < 64; o <<= 1) v += __shfl_xor(v, o, 64);
        if (lane == 0) out[DD] = logq_r - v;
    }
}

extern "C" void kernel_launch(void* const* d_in, const int* in_sizes, int n_in,
                              void* d_out, int out_size, void* d_ws, size_t ws_size,
                              hipStream_t stream) {
    const float* x0 = (const float*)d_in[0];
    const float* W1 = (const float*)d_in[1];
    const float* b1 = (const float*)d_in[2];
    const float* wt = (const float*)d_in[3];
    const float* W2 = (const float*)d_in[4];
    const float* b2 = (const float*)d_in[5];
    const float* W3 = (const float*)d_in[6];
    const float* b3 = (const float*)d_in[7];
    float* out = (float*)d_out;

    char* ws = (char*)d_ws;
    const size_t MB = 1024 * 1024;
    unsigned short* Pb  = (unsigned short*)(ws);            // 8 MB
    unsigned short* W2T = (unsigned short*)(ws + 8 * MB);   // 8 MB
    unsigned short* W3T = (unsigned short*)(ws + 16 * MB);  // 4 MB
    unsigned short* Mb  = (unsigned short*)(ws + 20 * MB);  // 8 MB
    unsigned short* W1T = (unsigned short*)(ws + 28 * MB);  // 4 MB
    unsigned short* W3b = (unsigned short*)(ws + 32 * MB);  // 4 MB
    float* fb = (float*)(ws + 36 * MB);
    float* c1      = fb;                       // 2048
    float* A1g     = fb + 2048;                // 2048
    float* h1_g    = fb + 4096;                // 2048
    float* h2_g    = fb + 6144;                // 2048
    float* hacc_g  = fb + 8192;                // 2048
    unsigned* sync = (unsigned*)(fb + 10240);  // 4368 uints

    k_tr<<<2048, 256, 0, stream>>>(W1, W2, W3, W1T, W2T, W3T, W3b, sync);
    k_gemmP<<<512, 256, 0, stream>>>(W1T, W3b, W2, b3, x0, Mb, Pb, c1, A1g);
    k_chain<<<NCB, 256, 0, stream>>>(Mb, Pb, W2T, W3T, x0, b1, wt, b2, b3, c1, A1g,
                                     h1_g, h2_g, hacc_g, out, sync);
}